// Round 19
// baseline (801.885 us; speedup 1.0000x reference)
//
#include <hip/hip_runtime.h>
#include <hip/hip_bf16.h>

#define S_LEN 1024
#define BATCH 8
#define HD 512
#define FFD 2048
#define NHEAD 4
#define NBLK 3
#define NTOK 128

typedef __bf16 bf16_t;
typedef __bf16 bf16x4_t __attribute__((ext_vector_type(4)));
typedef __bf16 bf16x8_t __attribute__((ext_vector_type(8)));
typedef float f32x4_t __attribute__((ext_vector_type(4)));

typedef __attribute__((address_space(3))) uint32_t lds_u32;
typedef __attribute__((address_space(1))) uint32_t glb_u32;

// ---- LDS fragment read: NI frags of 16 rows from row0, XOR-swizzled chunks ----
template<int NI>
__device__ __forceinline__ void ldsread(const bf16_t* __restrict__ buf, int row0,
                                        int fr, int fg, int sw, bf16x8_t (&dst)[NI][2]) {
  #pragma unroll
  for (int i = 0; i < NI; ++i)
    #pragma unroll
    for (int ks = 0; ks < 2; ++ks)
      dst[i][ks] = *(const bf16x8_t*)&buf[(row0 + i*16 + fr)*64 + (((ks*4 + fg) ^ sw) << 3)];
}

// ---- one C-quadrant x K=64: 16 MFMA ----
template<int IB, int JB>
__device__ __forceinline__ void mquad(f32x4_t (&acc)[8][4],
                                      const bf16x8_t (&af)[4][2], const bf16x8_t (&bf)[2][2]) {
  #pragma unroll
  for (int ks = 0; ks < 2; ++ks)
    #pragma unroll
    for (int i = 0; i < 4; ++i)
      #pragma unroll
      for (int j = 0; j < 2; ++j)
        acc[IB+i][JB+j] = __builtin_amdgcn_mfma_f32_16x16x32_bf16(af[i][ks], bf[j][ks], acc[IB+i][JB+j], 0, 0, 0);
}

// ================= 256x256 GEMM =================
// DB: r7 2-barrier/K-tile, 2-deep counted-vmcnt prefetch, 128KiB LDS, 1 blk/CU.
// launch_bounds (512,2): VGPR cap 128 (r8: arg 4 -> 64 VGPR -> acc spilled).
// TRI: blockIdx.x = lower-triangle tile index. bshift: B shared across 2^bshift z.
// KSPLIT (r18 PV balance, ordering fixed vs r17): kh lives in blockIdx.y high bit
//   (launch order x->y->z mixes kh within each dispatch wave -> HW backfill).
//   kh=0: K[0,min(K/2,kend)) -> slots 0-3; kh=1: K[K/2,kend) (m0<K/2 -> return)
//   -> slots 4-7 at coff + kh*sBias.
template<bool OUT_BF16, bool BIAS, bool RELU, bool TRI, bool CKLIM, bool NORM, bool KSPLIT>
__global__ __launch_bounds__(512, 2)
void gemm256_kernel(const bf16_t* __restrict__ A,
                    const bf16_t* __restrict__ Bt,
                    const float* __restrict__ bias,
                    void* __restrict__ Cv,
                    int M, int N, int K,
                    int lda, int ldb, int ldc,
                    long long sA, long long sB, int bshift, long long sBias,
                    int zshift, long long sC_hi, long long sC_lo,
                    int msub_shift, long long msub_stride,
                    float alpha)
{
  const int zb = blockIdx.z;
  int m0, n0, khh = 0;
  if (TRI) {
    const int idx = blockIdx.x;
    int mi = (int)((sqrtf(8.f * idx + 1.f) - 1.f) * 0.5f);
    while ((mi + 1) * (mi + 2) / 2 <= idx) ++mi;
    while (mi * (mi + 1) / 2 > idx) --mi;
    m0 = mi * 256;
    n0 = (idx - mi * (mi + 1) / 2) * 256;
  } else if (KSPLIT) {
    m0 = blockIdx.x * 256;
    n0 = (blockIdx.y & 1) * 256;
    khh = blockIdx.y >> 1;
  } else {
    m0 = blockIdx.x * 256;
    n0 = blockIdx.y * 256;
  }
  int kend = K;
  if (CKLIM) {
    int ke = m0 + 256;
    int kcap = (KSPLIT && khh == 0) ? (K >> 1) : K;
    kend = ke < kcap ? ke : kcap;
  }
  const int t0k = (KSPLIT && khh) ? (K >> 7) : 0;   // start K-tile = (K/2)/64
  if (KSPLIT && kend <= (t0k << 6)) return;          // residual empty
  const int nt = kend >> 6;

  const bf16_t* Az = A + (long long)zb * sA;
  const bf16_t* Bz = Bt + (long long)(zb >> bshift) * sB;
  long long coff = ((long long)(zb >> zshift)) * sC_hi
                 + ((long long)(zb & ((1 << zshift) - 1))) * sC_lo;
  if (KSPLIT) coff += (long long)khh * sBias;

  __shared__ __align__(16) bf16_t As[2][256 * 64];
  __shared__ __align__(16) bf16_t Bs[2][256 * 64];

  const int tid = threadIdx.x;          // 0..511
  const int lane = tid & 63;
  const int w = tid >> 6;               // 0..7
  const int wm = (w >> 2) * 128;        // 0,128
  const int wn = (w & 3) * 64;          // 0,64,128,192
  const int fr = lane & 15;
  const int fg = lane >> 4;
  const int sw = fr & 7;

  const int srow = tid >> 3;            // 0..63
  const int scol8 = tid & 7;
  const int gswz = ((scol8 ^ (srow & 7)) << 3);

  f32x4_t acc[8][4];
  #pragma unroll
  for (int i = 0; i < 8; ++i)
    #pragma unroll
    for (int j = 0; j < 4; ++j)
      acc[i][j] = (f32x4_t){0.f, 0.f, 0.f, 0.f};

  const bf16_t* gA0 = Az + (long long)(m0 + srow) * lda + gswz;
  const bf16_t* gB0 = Bz + (long long)(n0 + srow) * ldb + gswz;

  // stage one 128x64 half-tile (2 global_load_lds/thread). h:0=A0,1=A1,2=B0,3=B1
  auto stage_half = [&](int buf, int kt, int h) {
    if (h < 2) {
      const bf16_t* g = gA0 + (long long)(h * 128) * lda + (kt << 6);
      bf16_t* l = &As[buf][(h*128 + srow) * 64 + (scol8 << 3)];
      __builtin_amdgcn_global_load_lds((const glb_u32*)g, (lds_u32*)l, 16, 0, 0);
      __builtin_amdgcn_global_load_lds((const glb_u32*)(g + 64LL*lda), (lds_u32*)(l + 64*64), 16, 0, 0);
    } else {
      const int hh = h - 2;
      const bf16_t* g = gB0 + (long long)(hh * 128) * ldb + (kt << 6);
      bf16_t* l = &Bs[buf][(hh*128 + srow) * 64 + (scol8 << 3)];
      __builtin_amdgcn_global_load_lds((const glb_u32*)g, (lds_u32*)l, 16, 0, 0);
      __builtin_amdgcn_global_load_lds((const glb_u32*)(g + 64LL*ldb), (lds_u32*)(l + 64*64), 16, 0, 0);
    }
  };

  // prologue: full t0k + A-halves of t0k+1; wait first tile (next A's 4 loads fly)
  stage_half(0, t0k, 0); stage_half(0, t0k, 1); stage_half(0, t0k, 2); stage_half(0, t0k, 3);
  if (nt - t0k > 1) { stage_half(1, t0k + 1, 0); stage_half(1, t0k + 1, 1); }
  if (nt - t0k > 1) asm volatile("s_waitcnt vmcnt(4)" ::: "memory");
  else              asm volatile("s_waitcnt vmcnt(0)" ::: "memory");
  __builtin_amdgcn_s_barrier();
  __builtin_amdgcn_sched_barrier(0);

  for (int t = t0k; t < nt; ++t) {
    const int cur = (t - t0k) & 1;
    const bf16_t* Ac = &As[cur][0];
    const bf16_t* Bc = &Bs[cur][0];
    bf16x8_t a0[4][2], a1[4][2], b0[2][2], b1[2][2];

    // region 1: all LDS reads of tile t + B-stages of t+1 (other buffer)
    ldsread<4>(Ac, wm, fr, fg, sw, a0);
    ldsread<2>(Bc, wn, fr, fg, sw, b0);
    if (t + 1 < nt) stage_half(cur ^ 1, t + 1, 2);
    mquad<0, 0>(acc, a0, b0);
    ldsread<4>(Ac, wm + 64, fr, fg, sw, a1);
    ldsread<2>(Bc, wn + 32, fr, fg, sw, b1);
    if (t + 1 < nt) stage_half(cur ^ 1, t + 1, 3);
    mquad<4, 2>(acc, a1, b1);

    __builtin_amdgcn_s_barrier();        // all reads of buf cur consumed
    __builtin_amdgcn_sched_barrier(0);

    // region 2: register-only quads + A-stages of t+2 (into buf cur)
    if (t + 2 < nt) stage_half(cur, t + 2, 0);
    mquad<0, 2>(acc, a0, b1);
    if (t + 2 < nt) {
      stage_half(cur, t + 2, 1);
      asm volatile("s_waitcnt vmcnt(4)" ::: "memory");   // tile t+1 fully landed
    } else {
      asm volatile("s_waitcnt vmcnt(0)" ::: "memory");
    }
    mquad<4, 0>(acc, a1, b0);

    __builtin_amdgcn_s_barrier();        // collective: t+1 data visible to all
    __builtin_amdgcn_sched_barrier(0);
  }

  #pragma unroll
  for (int i = 0; i < 8; ++i) {
    #pragma unroll
    for (int e = 0; e < 4; ++e) {
      const int row = m0 + wm + i*16 + fg*4 + e;
      const long long ro = coff
        + ((long long)(row >> msub_shift)) * msub_stride
        + (long long)(row & ((1 << msub_shift) - 1)) * (long long)ldc;
      float rn = 1.f;
      if (NORM) rn = bias[(long long)zb * sBias + row];
      #pragma unroll
      for (int j = 0; j < 4; ++j) {
        const int col = n0 + wn + j*16 + fr;
        float v = acc[i][j][e] * alpha;
        if (BIAS) v += bias[(long long)zb * sBias + col];
        if (NORM) v *= rn;
        if (RELU) v = v > 0.f ? v : 0.f;
        if (OUT_BF16) ((bf16_t*)Cv)[ro + col] = (bf16_t)v;
        else          ((float*)Cv)[ro + col]  = v;
      }
    }
  }
}

// ================= 128x128 m97-style GEMM (scores, G-gemm, UT-gemm, lm head) ============
// (256,2): ~100 VGPR + 32KB LDS -> ~5 resident blocks/CU (fine-grain backfill).
// CSKIP: causal tile skip. bshift: B shared across 2^bshift z (scores: 4 heads/batch).
template<bool OUT_BF16, bool BIAS, bool RELU, bool CSKIP, bool CKLIM>
__global__ __launch_bounds__(256, 2)
void gemm_bt_kernel(const bf16_t* __restrict__ A,
                    const bf16_t* __restrict__ Bt,
                    const float* __restrict__ bias,
                    void* __restrict__ Cv,
                    int M, int N, int K,
                    int lda, int ldb, int ldc,
                    long long sA, long long sB, int bshift, long long sBias,
                    int zshift, long long sC_hi, long long sC_lo,
                    int msub_shift, long long msub_stride,
                    float alpha)
{
  const int zb = blockIdx.z;
  const int m0 = blockIdx.x * 128;
  const int n0 = blockIdx.y * 128;
  if (CSKIP && n0 > m0 + 127) return;
  int kend = K;
  if (CKLIM) { int ke = m0 + 128; kend = ke < K ? ke : K; }

  const bf16_t* Az = A + (long long)zb * sA;
  const bf16_t* Bz = Bt + (long long)(zb >> bshift) * sB;
  const long long coff = ((long long)(zb >> zshift)) * sC_hi
                       + ((long long)(zb & ((1 << zshift) - 1))) * sC_lo;

  __shared__ __align__(16) bf16_t As[128 * 64];
  __shared__ __align__(16) bf16_t Bs[128 * 64];

  const int tid = threadIdx.x;
  const int wv = tid >> 6;
  const int lane = tid & 63;
  const int wm = (wv >> 1) * 64;
  const int wn = (wv & 1) * 64;
  const int fr = lane & 15;
  const int fg = lane >> 4;
  const int sw = fr & 7;

  f32x4_t acc[4][4];
  #pragma unroll
  for (int i = 0; i < 4; ++i)
    #pragma unroll
    for (int j = 0; j < 4; ++j)
      acc[i][j] = (f32x4_t){0.f, 0.f, 0.f, 0.f};

  const bf16_t* ga = Az + (long long)(m0 + (wv << 5) + (lane >> 3)) * lda
                   + (((lane & 7) ^ (lane >> 3)) << 3);
  const bf16_t* gb = Bz + (long long)(n0 + (wv << 5) + (lane >> 3)) * ldb
                   + (((lane & 7) ^ (lane >> 3)) << 3);

  for (int k0 = 0; k0 < kend; k0 += 64) {
    #pragma unroll
    for (int s = 0; s < 4; ++s) {
      __builtin_amdgcn_global_load_lds(
        (const glb_u32*)(ga + (long long)s * 8 * lda + k0),
        (lds_u32*)(As + (wv * 4 + s) * 512), 16, 0, 0);
      __builtin_amdgcn_global_load_lds(
        (const glb_u32*)(gb + (long long)s * 8 * ldb + k0),
        (lds_u32*)(Bs + (wv * 4 + s) * 512), 16, 0, 0);
    }
    __syncthreads();
    #pragma unroll
    for (int kc = 0; kc < 2; ++kc) {
      const int ca = ((kc * 4 + fg) ^ sw) << 3;
      bf16x8_t af[4], bfr[4];
      #pragma unroll
      for (int i = 0; i < 4; ++i)
        af[i] = *(const bf16x8_t*)&As[(wm + i*16 + fr) * 64 + ca];
      #pragma unroll
      for (int j = 0; j < 4; ++j)
        bfr[j] = *(const bf16x8_t*)&Bs[(wn + j*16 + fr) * 64 + ca];
      #pragma unroll
      for (int i = 0; i < 4; ++i)
        #pragma unroll
        for (int j = 0; j < 4; ++j)
          acc[i][j] = __builtin_amdgcn_mfma_f32_16x16x32_bf16(af[i], bfr[j], acc[i][j], 0, 0, 0);
    }
    __syncthreads();
  }

  #pragma unroll
  for (int i = 0; i < 4; ++i) {
    #pragma unroll
    for (int e = 0; e < 4; ++e) {
      const int row = m0 + wm + i*16 + fg*4 + e;
      const long long ro = coff
        + ((long long)(row >> msub_shift)) * msub_stride
        + (long long)(row & ((1 << msub_shift) - 1)) * (long long)ldc;
      #pragma unroll
      for (int j = 0; j < 4; ++j) {
        const int col = n0 + wn + j*16 + fr;
        float v = acc[i][j][e] * alpha;
        if (BIAS) v += bias[(long long)zb * sBias + col];
        if (RELU) v = v > 0.f ? v : 0.f;
        if (OUT_BF16) ((bf16_t*)Cv)[ro + col] = (bf16_t)v;
        else          ((float*)Cv)[ro + col]  = v;
      }
    }
  }
}

// ---------------- softmax: ONE WAVE PER ROW, bf16 in-place, pure shfl reduce ----------------
__global__ void softmax_kernel(bf16_t* __restrict__ scP,
                               const int* __restrict__ mask, int pair0)
{
  const int lane = threadIdx.x & 63;
  const int s = blockIdx.x * 4 + (threadIdx.x >> 6);
  const int pz = blockIdx.y;
  const int b = (pair0 + pz) >> 2;
  bf16_t* row = scP + ((long long)pz * S_LEN + s) * S_LEN;
  const int t0 = lane * 16;

  bf16x8_t r0 = *(const bf16x8_t*)&row[t0];
  bf16x8_t r1 = *(const bf16x8_t*)&row[t0 + 8];
  int4 m4[4];
  #pragma unroll
  for (int q = 0; q < 4; ++q) m4[q] = *(const int4*)&mask[b * S_LEN + t0 + q*4];
  const int* mm = (const int*)m4;

  float v[16]; bool ok[16];
  #pragma unroll
  for (int j = 0; j < 16; ++j) {
    const int t = t0 + j;
    ok[j] = (t <= s) && (mm[j] != 0);
    float raw = (j < 8) ? (float)r0[j] : (float)r1[j - 8];
    v[j] = ok[j] ? raw : -INFINITY;
  }
  float mx = v[0];
  #pragma unroll
  for (int j = 1; j < 16; ++j) mx = fmaxf(mx, v[j]);
  #pragma unroll
  for (int o = 32; o; o >>= 1) mx = fmaxf(mx, __shfl_xor(mx, o));

  float e[16]; float sum = 0.f;
  #pragma unroll
  for (int j = 0; j < 16; ++j) { e[j] = ok[j] ? __expf(v[j] - mx) : 0.f; sum += e[j]; }
  #pragma unroll
  for (int o = 32; o; o >>= 1) sum += __shfl_xor(sum, o);

  const bool qvalid = mask[b * S_LEN + s] != 0;
  const float inv = (qvalid && sum > 0.f) ? 1.f / sum : 0.f;
  bf16x8_t o0, o1;
  #pragma unroll
  for (int j = 0; j < 8; ++j) { o0[j] = (bf16_t)(e[j] * inv); o1[j] = (bf16_t)(e[j+8] * inv); }
  *(bf16x8_t*)&row[t0] = o0;
  *(bf16x8_t*)&row[t0 + 8] = o1;
}

// ---------------- transpose (+cast to bf16): out[C][R] = in[R][C] ----------------
template<typename TIN>
__global__ void transpose_kernel(const TIN* __restrict__ in, bf16_t* __restrict__ out,
                                 int R, int C, long long sIn, long long sOut)
{
  __shared__ float tile[32][33];
  const long long zi = (long long)blockIdx.z * sIn;
  const long long zo = (long long)blockIdx.z * sOut;
  const int c0 = blockIdx.x * 32, r0 = blockIdx.y * 32;
  const int tx = threadIdx.x, ty = threadIdx.y;  // 32 x 8
  #pragma unroll
  for (int i = 0; i < 4; ++i) {
    int r = r0 + ty + i*8;
    tile[ty + i*8][tx] = (float)in[zi + (long long)r * C + c0 + tx];
  }
  __syncthreads();
  #pragma unroll
  for (int i = 0; i < 4; ++i) {
    int c = c0 + ty + i*8;
    out[zo + (long long)c * R + r0 + tx] = (bf16_t)tile[tx][ty + i*8];
  }
}

// ---------------- two-source f32 -> bf16 convert (out laid [a | b]) ----------------
__global__ void convert2_kernel(const float* __restrict__ a, const float* __restrict__ b,
                                bf16_t* __restrict__ out, long long n)
{
  long long i = (long long)blockIdx.x * blockDim.x + threadIdx.x;
  long long stride = (long long)gridDim.x * blockDim.x;
  for (; i < 2*n; i += stride)
    out[i] = (bf16_t)(i < n ? a[i] : b[i - n]);
}

// ---------------- diagnostic fill ----------------
__global__ void fill_kernel(float* __restrict__ out, long long n, float v)
{
  long long i = (long long)blockIdx.x * blockDim.x + threadIdx.x;
  long long stride = (long long)gridDim.x * blockDim.x;
  for (; i < n; i += stride) out[i] = v;
}

// ---------------- positions: pos = cumsum(mask) - 1 ----------------
__global__ void pos_kernel(const int* __restrict__ mask, float* __restrict__ pos)
{
  __shared__ float scn[S_LEN];
  const int b = blockIdx.x, t = threadIdx.x;
  scn[t] = (float)(mask[b * S_LEN + t] != 0);
  __syncthreads();
  for (int off = 1; off < S_LEN; off <<= 1) {
    float add = (t >= off) ? scn[t - off] : 0.f;
    __syncthreads();
    scn[t] += add;
    __syncthreads();
  }
  pos[b * S_LEN + t] = scn[t] - 1.0f;
}

// ---------------- embedding + positional encoding ----------------
__global__ void embed_kernel(const int* __restrict__ ids, const int* __restrict__ mask,
                             const float* __restrict__ pos, const float* __restrict__ emb,
                             float* __restrict__ x, bf16_t* __restrict__ xb)
{
  const int idx = blockIdx.x * 256 + threadIdx.x;
  const int i = idx & 255;
  const int bs = idx >> 8;
  const int id = ids[bs];
  const float m = (float)(mask[bs] != 0);
  const float p = pos[bs];
  const float dv = __expf(-(float)(2 * i) * (9.210340371976184f / (float)HD));
  const float sv = __sinf(p * dv) * m;
  const float e0 = emb[id * HD + 2*i], e1 = emb[id * HD + 2*i + 1];
  const float x0 = e0 + sv, x1 = e1 + sv;
  x[(long long)bs * HD + 2*i]     = x0;
  x[(long long)bs * HD + 2*i + 1] = x1;
  xb[(long long)bs * HD + 2*i]     = (bf16_t)x0;
  xb[(long long)bs * HD + 2*i + 1] = (bf16_t)x1;
}

// ---------------- layernorm, f32 partials (FF path) ----------------
__global__ void ln_kernel(float* __restrict__ x, const float* __restrict__ tparts,
                          int ns, long long pstride,
                          const float* __restrict__ bias,
                          const float* __restrict__ g, const float* __restrict__ b,
                          bf16_t* __restrict__ xb)
{
  const int lane = threadIdx.x & 63;
  const long long row = (long long)blockIdx.x * 4 + (threadIdx.x >> 6);
  const int e0 = lane * 8;
  const long long base = row * HD + e0;

  float4 xa = *(const float4*)&x[base];
  float4 xc = *(const float4*)&x[base + 4];
  float4 ba = *(const float4*)&bias[e0];
  float4 bc = *(const float4*)&bias[e0 + 4];
  float v[8] = {xa.x+ba.x, xa.y+ba.y, xa.z+ba.z, xa.w+ba.w,
                xc.x+bc.x, xc.y+bc.y, xc.z+bc.z, xc.w+bc.w};
  for (int i = 0; i < ns; ++i) {
    float4 p0 = *(const float4*)&tparts[i*pstride + base];
    float4 p1 = *(const float4*)&tparts[i*pstride + base + 4];
    v[0]+=p0.x; v[1]+=p0.y; v[2]+=p0.z; v[3]+=p0.w;
    v[4]+=p1.x; v[5]+=p1.y; v[6]+=p1.z; v[7]+=p1.w;
  }
  float s = 0.f;
  #pragma unroll
  for (int j = 0; j < 8; ++j) s += v[j];
  #pragma unroll
  for (int o = 32; o; o >>= 1) s += __shfl_xor(s, o);
  const float mu = s * (1.f / (float)HD);
  float q = 0.f;
  #pragma unroll
  for (int j = 0; j < 8; ++j) { v[j] -= mu; q += v[j]*v[j]; }
  #pragma unroll
  for (int o = 32; o; o >>= 1) q += __shfl_xor(q, o);
  const float inv = rsqrtf(q * (1.f / (float)HD) + 1e-5f);

  float4 ga4 = *(const float4*)&g[e0];
  float4 gc4 = *(const float4*)&g[e0 + 4];
  float4 bb4 = *(const float4*)&b[e0];
  float4 bd4 = *(const float4*)&b[e0 + 4];
  float y[8] = {v[0]*inv*ga4.x+bb4.x, v[1]*inv*ga4.y+bb4.y, v[2]*inv*ga4.z+bb4.z, v[3]*inv*ga4.w+bb4.w,
                v[4]*inv*gc4.x+bd4.x, v[5]*inv*gc4.y+bd4.y, v[6]*inv*gc4.z+bd4.z, v[7]*inv*gc4.w+bd4.w};
  *(float4*)&x[base]     = (float4){y[0],y[1],y[2],y[3]};
  *(float4*)&x[base + 4] = (float4){y[4],y[5],y[6],y[7]};
  bf16x8_t yb;
  #pragma unroll
  for (int j = 0; j < 8; ++j) yb[j] = (bf16_t)y[j];
  *(bf16x8_t*)&xb[base] = yb;
}

// ---------------- layernorm, bf16 partials (attention path) ----------------
// Slots 0..3 always; slots 4..7 only for rows with s>=512 (KSPLIT residual).
__global__ void lnb_kernel(float* __restrict__ x, const bf16_t* __restrict__ tparts,
                           long long pstride, int nsl_hi,
                           const float* __restrict__ bias,
                           const float* __restrict__ g, const float* __restrict__ b,
                           bf16_t* __restrict__ xb)
{
  const int lane = threadIdx.x & 63;
  const long long row = (long long)blockIdx.x * 4 + (threadIdx.x >> 6);
  const int e0 = lane * 8;
  const long long base = row * HD + e0;
  const int s_in_seq = (int)(row & (S_LEN - 1));
  const int nsl = (s_in_seq >= 512) ? nsl_hi : 4;

  float4 xa = *(const float4*)&x[base];
  float4 xc = *(const float4*)&x[base + 4];
  float4 ba = *(const float4*)&bias[e0];
  float4 bc = *(const float4*)&bias[e0 + 4];
  float v[8] = {xa.x+ba.x, xa.y+ba.y, xa.z+ba.z, xa.w+ba.w,
                xc.x+bc.x, xc.y+bc.y, xc.z+bc.z, xc.w+bc.w};
  for (int i = 0; i < nsl; ++i) {
    bf16x8_t pp = *(const bf16x8_t*)&tparts[i*pstride + base];
    #pragma unroll
    for (int j = 0; j < 8; ++j) v[j] += (float)pp[j];
  }
  float s = 0.f;
  #pragma unroll
  for (int j = 0; j < 8; ++j) s += v[j];
  #pragma unroll
  for (int o = 32; o; o >>= 1) s += __shfl_xor(s, o);
  const float mu = s * (1.f / (float)HD);
  float q = 0.f;
  #pragma unroll
  for (int j = 0; j < 8; ++j) { v[j] -= mu; q += v[j]*v[j]; }
  #pragma unroll
  for (int o = 32; o; o >>= 1) q += __shfl_xor(q, o);
  const float inv = rsqrtf(q * (1.f / (float)HD) + 1e-5f);

  float4 ga4 = *(const float4*)&g[e0];
  float4 gc4 = *(const float4*)&g[e0 + 4];
  float4 bb4 = *(const float4*)&b[e0];
  float4 bd4 = *(const float4*)&b[e0 + 4];
  float y[8] = {v[0]*inv*ga4.x+bb4.x, v[1]*inv*ga4.y+bb4.y, v[2]*inv*ga4.z+bb4.z, v[3]*inv*ga4.w+bb4.w,
                v[4]*inv*gc4.x+bd4.x, v[5]*inv*gc4.y+bd4.y, v[6]*inv*gc4.z+bd4.z, v[7]*inv*gc4.w+bd4.w};
  *(float4*)&x[base]     = (float4){y[0],y[1],y[2],y[3]};
  *(float4*)&x[base + 4] = (float4){y[4],y[5],y[6],y[7]};
  bf16x8_t yb;
  #pragma unroll
  for (int j = 0; j < 8; ++j) yb[j] = (bf16_t)y[j];
  *(bf16x8_t*)&xb[base] = yb;
}

extern "C" void kernel_launch(void* const* d_in, const int* in_sizes, int n_in,
                              void* d_out, int out_size, void* d_ws, size_t ws_size,
                              hipStream_t stream)
{
  (void)in_sizes; (void)n_in;
  const int*   ids   = (const int*)d_in[0];
  const int*   amask = (const int*)d_in[1];
  const float* emb   = (const float*)d_in[2];
  const float* wq    = (const float*)d_in[3];
  const float* wk    = (const float*)d_in[4];
  const float* wv    = (const float*)d_in[5];
  const float* wo_w  = (const float*)d_in[6];
  const float* wo_b  = (const float*)d_in[7];
  const float* ln1_g = (const float*)d_in[8];
  const float* ln1_b = (const float*)d_in[9];
  const float* ff1_w = (const float*)d_in[10];
  const float* ff1_b = (const float*)d_in[11];
  const float* ff2_w = (const float*)d_in[12];
  const float* ff2_b = (const float*)d_in[13];
  const float* ln2_g = (const float*)d_in[14];
  const float* ln2_b = (const float*)d_in[15];
  const float* lm_w  = (const float*)d_in[16];

  const long long MROW = (long long)BATCH * S_LEN;   // 8192
  const size_t MBc = 1ull << 20;
  char* p = (char*)d_ws;
  auto alloc = [&](size_t bytes) { char* r = p; p += (bytes + 255) & ~(size_t)255; return r; };

  // persistent (~113 MB): all-layer weights prepped ONCE upfront (r18)
  float*  x     = (float*) alloc(MROW * HD * 4);                // 16 MB
  bf16_t* xb    = (bf16_t*)alloc(MROW * HD * 2);                // 8 MB
  bf16_t* ob    = (bf16_t*)alloc(8LL * MROW * HD * 2);          // 64 MB: 8 partial slots
  bf16_t* Gt3   = (bf16_t*)alloc(12LL * HD * HD * 2);           // 6 MB  Gt[l][h][n][a]
  bf16_t* UT3   = (bf16_t*)alloc(12LL * HD * HD * 2);           // 6 MB  UT[l][h][f][c]
  bf16_t* wffa  = (bf16_t*)alloc(6LL * FFD * HD * 2);           // 12 MB [ff1 l0..2 | ff2 l0..2]
  bf16_t* lmT   = (bf16_t*)alloc((long long)NTOK * HD * 2);
  float*  pos   = (float*) alloc(MROW * 4);

  const size_t used = (size_t)(p - (char*)d_ws);
  const size_t rem  = ws_size > used ? ws_size - used : 0;

  // attn region: P*(y 1MB + uT 1MB) + P*2MB scores;  FF region SK*16+32 MB (aliased)
  int P = 0, SK = 2;
  if      (rem >= 128 * MBc) { P = 32; SK = 4; }  // attn 128 MB, FF 96 MB
  else if (rem >= 64 * MBc)  { P = 8;  SK = 2; }  // attn 32 MB, FF 64 MB
  if (P == 0) {
    fill_kernel<<<1024, 256, 0, stream>>>((float*)d_out, (long long)out_size,
                                          (float)(ws_size >> 20));
    return;
  }

  char* A = p;
  const long long pairE = (long long)S_LEN * HD;
  bf16_t* qc  = (bf16_t*)A;                        // y per pair
  bf16_t* uTc = qc  + (long long)P * pairE;        // uT per pair (u = x@U, U=Wv@Wo)
  bf16_t* scb = uTc + (long long)P * pairE;        // bf16 scores, softmax in-place
  float*  tmp = (float*)A;                          // FF phase aliases (SK partials)
  bf16_t* ffb = (bf16_t*)(A + (size_t)SK * 16 * MBc);
  // prep scratch (in A; dead once layer loop starts)
  bf16_t* wqkb = (bf16_t*)A;                        // 24 MB
  bf16_t* wvb  = wqkb + 24LL * HD * HD;             // 6 MB
  bf16_t* woTa = wvb  + 12LL * HD * HD;             // 6 MB (3x [HD][FFD])

  const dim3 tb(32, 8);
  // -------- one-time weight prep (batched over all 3 layers) --------
  transpose_kernel<float><<<dim3(4,16,1), tb, 0, stream>>>(lm_w, lmT, HD, NTOK, 0, 0);
  convert2_kernel<<<4096, 256, 0, stream>>>(wq, wk, wqkb, 12LL*HD*HD);
  convert2_kernel<<<2048, 256, 0, stream>>>(wv, wv + 6LL*HD*HD, wvb, 6LL*HD*HD);
  transpose_kernel<float><<<dim3(16,64,3), tb, 0, stream>>>(
    wo_w, woTa, FFD, HD, (long long)FFD*HD, (long long)HD*FFD);
  convert2_kernel<<<4096, 256, 0, stream>>>(ff1_w, ff2_w, wffa, 3LL*FFD*HD);
  // Gt[l*4+h] = Wk[l,h] @ Wq[l,h]^T  (z=12)
  gemm_bt_kernel<true,false,false,false,false><<<dim3(4,4,12),256,0,stream>>>(
    wqkb + 12LL*HD*HD, wqkb, nullptr, Gt3,
    HD, HD, HD, HD, HD, HD,
    (long long)HD*HD, (long long)HD*HD, 0, 0,
    30, 0, (long long)HD*HD,
    30, 0, 1.f);
  // UT[l*4+h] = (Wv[l,h] @ Wo[l])^T
  for (int l = 0; l < NBLK; ++l)
    gemm_bt_kernel<true,false,false,false,false><<<dim3(4,4,4),256,0,stream>>>(
      woTa + (long long)l*HD*FFD, wvb + (long long)l*4*HD*HD, nullptr,
      UT3 + (long long)l*4*HD*HD,
      HD, HD, HD, FFD, HD, HD,
      512, (long long)HD*HD, 0, 0,
      30, 0, (long long)HD*HD,
      30, 0, 1.f);

  pos_kernel<<<BATCH, S_LEN, 0, stream>>>(amask, pos);
  embed_kernel<<<8192, 256, 0, stream>>>(ids, amask, pos, emb, x, xb);

  const int nch = 32 / P;
  const int bpc = P / NHEAD;

  for (int l = 0; l < NBLK; ++l) {
    const bf16_t* Gt  = Gt3 + (long long)l*4*HD*HD;
    const bf16_t* UT  = UT3 + (long long)l*4*HD*HD;
    const bf16_t* wf1 = wffa + (long long)l*FFD*HD;
    const bf16_t* wf2 = wffa + 3LL*FFD*HD + (long long)l*HD*FFD;

    for (int c = 0; c < nch; ++c) {
      const int b0 = c * bpc;
      const int pair0 = b0 * NHEAD;
      const int Mch = bpc * S_LEN;

      // y = x @ G per head (z = head): replaces q AND k projections
      gemm256_kernel<true,false,false,false,false,false,false><<<dim3(Mch/256,2,4),512,0,stream>>>(
        xb + (long long)b0*S_LEN*HD, Gt, nullptr, qc, Mch, HD, HD, HD, HD, HD,
        0, (long long)HD*HD, 0, 0,
        2, 0, pairE,
        10, (long long)NHEAD*pairE, 1.f);

      // uT[pair][f][t] = sum_c UT[h][f][c] * xb[b,t,c]   (u = x@U; PV B-operand)
      gemm256_kernel<true,false,false,false,false,false,false><<<dim3(8,4,bpc),512,0,stream>>>(
        UT, xb + (long long)b0*S_LEN*HD, nullptr, uTc,
        2048, S_LEN, HD, HD, HD, S_LEN,
        0, (long long)S_LEN*HD, 0, 0,
        0, (long long)NHEAD*HD*S_LEN, 0,
        9, (long long)HD*S_LEN, 1.f);

      // scores = y @ xb^T / sqrt(512) -> bf16 scb. 128^2 tiles (CSKIP causal),
      // fine-grain backfill (r16). B shared per 4 heads.
      gemm_bt_kernel<true,false,false,true,false><<<dim3(8,8,P),256,0,stream>>>(
        qc, xb + (long long)b0*S_LEN*HD, nullptr, scb,
        S_LEN, S_LEN, HD, HD, HD, S_LEN,
        pairE, (long long)S_LEN*HD, 2, 0,
        30, 0, (long long)S_LEN*S_LEN,
        30, 0, 0.044194173824159216f);
      softmax_kernel<<<dim3(S_LEN/4,P),256,0,stream>>>(scb, amask, pair0);

      if (P == 32) {
        // K-SPLIT PV with kh in blockIdx.y (launch-order mixed -> HW backfill):
        // grid (4, 4, 32): y = kh*2 + n. Balanced <=8 K-tiles/block.
        gemm256_kernel<true,false,false,false,true,false,true><<<dim3(4,4,32),512,0,stream>>>(
          scb, uTc, nullptr, ob,
          S_LEN, HD, S_LEN, S_LEN, S_LEN, HD,
          (long long)S_LEN*S_LEN, (long long)HD*S_LEN, 0, 4LL*MROW*HD,
          2, (long long)S_LEN*HD, (long long)MROW*HD,
          30, 0, 1.f);
      } else {
        // fallback: unsplit PV into slots 0-3
        gemm256_kernel<true,false,false,false,true,false,false><<<dim3(4,2,P),512,0,stream>>>(
          scb, uTc, nullptr, ob + (long long)b0*S_LEN*HD,
          S_LEN, HD, S_LEN, S_LEN, S_LEN, HD,
          (long long)S_LEN*S_LEN, (long long)HD*S_LEN, 0, 0,
          2, (long long)S_LEN*HD, (long long)MROW*HD,
          30, 0, 1.f);
      }
    }

    // x = LN(x + sum_slots ob + wo_b)  (wo GEMM folded into U)
    lnb_kernel<<<2048,256,0,stream>>>(x, ob, (long long)MROW*HD, (P == 32) ? 8 : 4,
                                      wo_b + l*HD, ln1_g + l*HD, ln1_b + l*HD, xb);

    // ff1: relu(xb @ ff1^T + b1) -> ffb (bf16)
    gemm256_kernel<true,true,true,false,false,false,false><<<dim3(32,8,1),512,0,stream>>>(
      xb, wf1, ff1_b + l*FFD, ffb,
      (int)MROW, FFD, HD, HD, HD, FFD,
      0, 0, 0, 0, 30, 0, 0, 30, 0, 1.f);
    // ff2 (split-K=SK)
    gemm256_kernel<false,false,false,false,false,false,false><<<dim3(32,2,SK),512,0,stream>>>(
      ffb, wf2, nullptr, tmp,
      (int)MROW, HD, FFD/SK, FFD, FFD, HD,
      FFD/SK, FFD/SK, 0, 0,
      0, (long long)MROW*HD, 0,
      30, 0, 1.f);
    ln_kernel<<<2048,256,0,stream>>>(x, tmp, SK, (long long)MROW*HD,
                                     ff2_b + l*HD, ln2_g + l*HD, ln2_b + l*HD, xb);
  }

  // lm head -> d_out (f32), N=128 -> 128-tile kernel
  gemm_bt_kernel<false,false,false,false,false><<<dim3(64,1,1),256,0,stream>>>(
    xb, lmT, nullptr, (float*)d_out,
    (int)MROW, NTOK, HD, HD, HD, NTOK,
    0, 0, 0, 0, 30, 0, 0, 30, 0, 1.f);
}

// Round 20
// 768.773 us; speedup vs baseline: 1.0431x; 1.0431x over previous
//
#include <hip/hip_runtime.h>
#include <hip/hip_bf16.h>

#define S_LEN 1024
#define BATCH 8
#define HD 512
#define FFD 2048
#define NHEAD 4
#define NBLK 3
#define NTOK 128

typedef __bf16 bf16_t;
typedef __bf16 bf16x4_t __attribute__((ext_vector_type(4)));
typedef __bf16 bf16x8_t __attribute__((ext_vector_type(8)));
typedef float f32x4_t __attribute__((ext_vector_type(4)));

typedef __attribute__((address_space(3))) uint32_t lds_u32;
typedef __attribute__((address_space(1))) uint32_t glb_u32;

// ---- LDS fragment read: NI frags of 16 rows from row0, XOR-swizzled chunks ----
template<int NI>
__device__ __forceinline__ void ldsread(const bf16_t* __restrict__ buf, int row0,
                                        int fr, int fg, int sw, bf16x8_t (&dst)[NI][2]) {
  #pragma unroll
  for (int i = 0; i < NI; ++i)
    #pragma unroll
    for (int ks = 0; ks < 2; ++ks)
      dst[i][ks] = *(const bf16x8_t*)&buf[(row0 + i*16 + fr)*64 + (((ks*4 + fg) ^ sw) << 3)];
}

// ---- one C-quadrant x K=64: 16 MFMA ----
template<int IB, int JB>
__device__ __forceinline__ void mquad(f32x4_t (&acc)[8][4],
                                      const bf16x8_t (&af)[4][2], const bf16x8_t (&bf)[2][2]) {
  #pragma unroll
  for (int ks = 0; ks < 2; ++ks)
    #pragma unroll
    for (int i = 0; i < 4; ++i)
      #pragma unroll
      for (int j = 0; j < 2; ++j)
        acc[IB+i][JB+j] = __builtin_amdgcn_mfma_f32_16x16x32_bf16(af[i][ks], bf[j][ks], acc[IB+i][JB+j], 0, 0, 0);
}

// ================= 256x256 GEMM (r16 configuration, 765us best — frozen) =================
// DB: r7 2-barrier/K-tile, 2-deep counted-vmcnt prefetch, 128KiB LDS, 1 blk/CU.
// launch_bounds (512,2): VGPR cap 128 (r8: arg 4 -> 64 VGPR -> acc spilled).
// r13/r17/r19: epilogue or pipeline template edits perturb codegen (rule #19) — frozen.
// TRI: blockIdx.x = lower-triangle tile index. bshift: B shared across 2^bshift z.
template<bool OUT_BF16, bool BIAS, bool RELU, bool TRI, bool CKLIM, bool NORM>
__global__ __launch_bounds__(512, 2)
void gemm256_kernel(const bf16_t* __restrict__ A,
                    const bf16_t* __restrict__ Bt,
                    const float* __restrict__ bias,
                    void* __restrict__ Cv,
                    int M, int N, int K,
                    int lda, int ldb, int ldc,
                    long long sA, long long sB, int bshift, long long sBias,
                    int zshift, long long sC_hi, long long sC_lo,
                    int msub_shift, long long msub_stride,
                    float alpha)
{
  const int zb = blockIdx.z;
  int m0, n0;
  if (TRI) {
    const int idx = blockIdx.x;
    int mi = (int)((sqrtf(8.f * idx + 1.f) - 1.f) * 0.5f);
    while ((mi + 1) * (mi + 2) / 2 <= idx) ++mi;
    while (mi * (mi + 1) / 2 > idx) --mi;
    m0 = mi * 256;
    n0 = (idx - mi * (mi + 1) / 2) * 256;
  } else {
    m0 = blockIdx.x * 256;
    n0 = blockIdx.y * 256;
  }
  int kend = K;
  if (CKLIM) { int ke = m0 + 256; kend = ke < K ? ke : K; }
  const int nt = kend >> 6;

  const bf16_t* Az = A + (long long)zb * sA;
  const bf16_t* Bz = Bt + (long long)(zb >> bshift) * sB;
  const long long coff = ((long long)(zb >> zshift)) * sC_hi
                       + ((long long)(zb & ((1 << zshift) - 1))) * sC_lo;

  __shared__ __align__(16) bf16_t As[2][256 * 64];
  __shared__ __align__(16) bf16_t Bs[2][256 * 64];

  const int tid = threadIdx.x;          // 0..511
  const int lane = tid & 63;
  const int w = tid >> 6;               // 0..7
  const int wm = (w >> 2) * 128;        // 0,128
  const int wn = (w & 3) * 64;          // 0,64,128,192
  const int fr = lane & 15;
  const int fg = lane >> 4;
  const int sw = fr & 7;

  const int srow = tid >> 3;            // 0..63
  const int scol8 = tid & 7;
  const int gswz = ((scol8 ^ (srow & 7)) << 3);

  f32x4_t acc[8][4];
  #pragma unroll
  for (int i = 0; i < 8; ++i)
    #pragma unroll
    for (int j = 0; j < 4; ++j)
      acc[i][j] = (f32x4_t){0.f, 0.f, 0.f, 0.f};

  const bf16_t* gA0 = Az + (long long)(m0 + srow) * lda + gswz;
  const bf16_t* gB0 = Bz + (long long)(n0 + srow) * ldb + gswz;

  // stage one 128x64 half-tile (2 global_load_lds/thread). h:0=A0,1=A1,2=B0,3=B1
  auto stage_half = [&](int buf, int kt, int h) {
    if (h < 2) {
      const bf16_t* g = gA0 + (long long)(h * 128) * lda + (kt << 6);
      bf16_t* l = &As[buf][(h*128 + srow) * 64 + (scol8 << 3)];
      __builtin_amdgcn_global_load_lds((const glb_u32*)g, (lds_u32*)l, 16, 0, 0);
      __builtin_amdgcn_global_load_lds((const glb_u32*)(g + 64LL*lda), (lds_u32*)(l + 64*64), 16, 0, 0);
    } else {
      const int hh = h - 2;
      const bf16_t* g = gB0 + (long long)(hh * 128) * ldb + (kt << 6);
      bf16_t* l = &Bs[buf][(hh*128 + srow) * 64 + (scol8 << 3)];
      __builtin_amdgcn_global_load_lds((const glb_u32*)g, (lds_u32*)l, 16, 0, 0);
      __builtin_amdgcn_global_load_lds((const glb_u32*)(g + 64LL*ldb), (lds_u32*)(l + 64*64), 16, 0, 0);
    }
  };

  // prologue: full t0 + A-halves of t1; wait t0 landed (A(t1)'s 4 loads in flight)
  stage_half(0, 0, 0); stage_half(0, 0, 1); stage_half(0, 0, 2); stage_half(0, 0, 3);
  if (nt > 1) { stage_half(1, 1, 0); stage_half(1, 1, 1); }
  if (nt > 1) asm volatile("s_waitcnt vmcnt(4)" ::: "memory");
  else        asm volatile("s_waitcnt vmcnt(0)" ::: "memory");
  __builtin_amdgcn_s_barrier();
  __builtin_amdgcn_sched_barrier(0);

  for (int t = 0; t < nt; ++t) {
    const int cur = t & 1;
    const bf16_t* Ac = &As[cur][0];
    const bf16_t* Bc = &Bs[cur][0];
    bf16x8_t a0[4][2], a1[4][2], b0[2][2], b1[2][2];

    // region 1: all LDS reads of tile t + B-stages of t+1 (other buffer)
    ldsread<4>(Ac, wm, fr, fg, sw, a0);
    ldsread<2>(Bc, wn, fr, fg, sw, b0);
    if (t + 1 < nt) stage_half(cur ^ 1, t + 1, 2);
    mquad<0, 0>(acc, a0, b0);
    ldsread<4>(Ac, wm + 64, fr, fg, sw, a1);
    ldsread<2>(Bc, wn + 32, fr, fg, sw, b1);
    if (t + 1 < nt) stage_half(cur ^ 1, t + 1, 3);
    mquad<4, 2>(acc, a1, b1);

    __builtin_amdgcn_s_barrier();        // all reads of buf cur consumed
    __builtin_amdgcn_sched_barrier(0);

    // region 2: register-only quads + A-stages of t+2 (into buf cur)
    if (t + 2 < nt) stage_half(cur, t + 2, 0);
    mquad<0, 2>(acc, a0, b1);
    if (t + 2 < nt) {
      stage_half(cur, t + 2, 1);
      asm volatile("s_waitcnt vmcnt(4)" ::: "memory");   // tile t+1 fully landed
    } else {
      asm volatile("s_waitcnt vmcnt(0)" ::: "memory");
    }
    mquad<4, 0>(acc, a1, b0);

    __builtin_amdgcn_s_barrier();        // collective: t+1 data visible to all
    __builtin_amdgcn_sched_barrier(0);
  }

  #pragma unroll
  for (int i = 0; i < 8; ++i) {
    #pragma unroll
    for (int e = 0; e < 4; ++e) {
      const int row = m0 + wm + i*16 + fg*4 + e;
      const long long ro = coff
        + ((long long)(row >> msub_shift)) * msub_stride
        + (long long)(row & ((1 << msub_shift) - 1)) * (long long)ldc;
      float rn = 1.f;
      if (NORM) rn = bias[(long long)zb * sBias + row];
      #pragma unroll
      for (int j = 0; j < 4; ++j) {
        const int col = n0 + wn + j*16 + fr;
        float v = acc[i][j][e] * alpha;
        if (BIAS) v += bias[(long long)zb * sBias + col];
        if (NORM) v *= rn;
        if (RELU) v = v > 0.f ? v : 0.f;
        if (OUT_BF16) ((bf16_t*)Cv)[ro + col] = (bf16_t)v;
        else          ((float*)Cv)[ro + col]  = v;
      }
    }
  }
}

// ================= 128x128 m97-style GEMM (scores, G-gemm, UT-gemm, lm head) ============
// (256,2): ~100 VGPR + 32KB LDS -> ~5 resident blocks/CU (fine-grain backfill).
// CSKIP: causal tile skip. bshift: B shared across 2^bshift z (scores: 4 heads/batch).
template<bool OUT_BF16, bool BIAS, bool RELU, bool CSKIP, bool CKLIM>
__global__ __launch_bounds__(256, 2)
void gemm_bt_kernel(const bf16_t* __restrict__ A,
                    const bf16_t* __restrict__ Bt,
                    const float* __restrict__ bias,
                    void* __restrict__ Cv,
                    int M, int N, int K,
                    int lda, int ldb, int ldc,
                    long long sA, long long sB, int bshift, long long sBias,
                    int zshift, long long sC_hi, long long sC_lo,
                    int msub_shift, long long msub_stride,
                    float alpha)
{
  const int zb = blockIdx.z;
  const int m0 = blockIdx.x * 128;
  const int n0 = blockIdx.y * 128;
  if (CSKIP && n0 > m0 + 127) return;
  int kend = K;
  if (CKLIM) { int ke = m0 + 128; kend = ke < K ? ke : K; }

  const bf16_t* Az = A + (long long)zb * sA;
  const bf16_t* Bz = Bt + (long long)(zb >> bshift) * sB;
  const long long coff = ((long long)(zb >> zshift)) * sC_hi
                       + ((long long)(zb & ((1 << zshift) - 1))) * sC_lo;

  __shared__ __align__(16) bf16_t As[128 * 64];
  __shared__ __align__(16) bf16_t Bs[128 * 64];

  const int tid = threadIdx.x;
  const int wv = tid >> 6;
  const int lane = tid & 63;
  const int wm = (wv >> 1) * 64;
  const int wn = (wv & 1) * 64;
  const int fr = lane & 15;
  const int fg = lane >> 4;
  const int sw = fr & 7;

  f32x4_t acc[4][4];
  #pragma unroll
  for (int i = 0; i < 4; ++i)
    #pragma unroll
    for (int j = 0; j < 4; ++j)
      acc[i][j] = (f32x4_t){0.f, 0.f, 0.f, 0.f};

  const bf16_t* ga = Az + (long long)(m0 + (wv << 5) + (lane >> 3)) * lda
                   + (((lane & 7) ^ (lane >> 3)) << 3);
  const bf16_t* gb = Bz + (long long)(n0 + (wv << 5) + (lane >> 3)) * ldb
                   + (((lane & 7) ^ (lane >> 3)) << 3);

  for (int k0 = 0; k0 < kend; k0 += 64) {
    #pragma unroll
    for (int s = 0; s < 4; ++s) {
      __builtin_amdgcn_global_load_lds(
        (const glb_u32*)(ga + (long long)s * 8 * lda + k0),
        (lds_u32*)(As + (wv * 4 + s) * 512), 16, 0, 0);
      __builtin_amdgcn_global_load_lds(
        (const glb_u32*)(gb + (long long)s * 8 * ldb + k0),
        (lds_u32*)(Bs + (wv * 4 + s) * 512), 16, 0, 0);
    }
    __syncthreads();
    #pragma unroll
    for (int kc = 0; kc < 2; ++kc) {
      const int ca = ((kc * 4 + fg) ^ sw) << 3;
      bf16x8_t af[4], bfr[4];
      #pragma unroll
      for (int i = 0; i < 4; ++i)
        af[i] = *(const bf16x8_t*)&As[(wm + i*16 + fr) * 64 + ca];
      #pragma unroll
      for (int j = 0; j < 4; ++j)
        bfr[j] = *(const bf16x8_t*)&Bs[(wn + j*16 + fr) * 64 + ca];
      #pragma unroll
      for (int i = 0; i < 4; ++i)
        #pragma unroll
        for (int j = 0; j < 4; ++j)
          acc[i][j] = __builtin_amdgcn_mfma_f32_16x16x32_bf16(af[i], bfr[j], acc[i][j], 0, 0, 0);
    }
    __syncthreads();
  }

  #pragma unroll
  for (int i = 0; i < 4; ++i) {
    #pragma unroll
    for (int e = 0; e < 4; ++e) {
      const int row = m0 + wm + i*16 + fg*4 + e;
      const long long ro = coff
        + ((long long)(row >> msub_shift)) * msub_stride
        + (long long)(row & ((1 << msub_shift) - 1)) * (long long)ldc;
      #pragma unroll
      for (int j = 0; j < 4; ++j) {
        const int col = n0 + wn + j*16 + fr;
        float v = acc[i][j][e] * alpha;
        if (BIAS) v += bias[(long long)zb * sBias + col];
        if (RELU) v = v > 0.f ? v : 0.f;
        if (OUT_BF16) ((bf16_t*)Cv)[ro + col] = (bf16_t)v;
        else          ((float*)Cv)[ro + col]  = v;
      }
    }
  }
}

// ---------------- softmax: ONE WAVE PER ROW, bf16 in-place, pure shfl reduce ----------------
__global__ void softmax_kernel(bf16_t* __restrict__ scP,
                               const int* __restrict__ mask, int pair0)
{
  const int lane = threadIdx.x & 63;
  const int s = blockIdx.x * 4 + (threadIdx.x >> 6);
  const int pz = blockIdx.y;
  const int b = (pair0 + pz) >> 2;
  bf16_t* row = scP + ((long long)pz * S_LEN + s) * S_LEN;
  const int t0 = lane * 16;

  bf16x8_t r0 = *(const bf16x8_t*)&row[t0];
  bf16x8_t r1 = *(const bf16x8_t*)&row[t0 + 8];
  int4 m4[4];
  #pragma unroll
  for (int q = 0; q < 4; ++q) m4[q] = *(const int4*)&mask[b * S_LEN + t0 + q*4];
  const int* mm = (const int*)m4;

  float v[16]; bool ok[16];
  #pragma unroll
  for (int j = 0; j < 16; ++j) {
    const int t = t0 + j;
    ok[j] = (t <= s) && (mm[j] != 0);
    float raw = (j < 8) ? (float)r0[j] : (float)r1[j - 8];
    v[j] = ok[j] ? raw : -INFINITY;
  }
  float mx = v[0];
  #pragma unroll
  for (int j = 1; j < 16; ++j) mx = fmaxf(mx, v[j]);
  #pragma unroll
  for (int o = 32; o; o >>= 1) mx = fmaxf(mx, __shfl_xor(mx, o));

  float e[16]; float sum = 0.f;
  #pragma unroll
  for (int j = 0; j < 16; ++j) { e[j] = ok[j] ? __expf(v[j] - mx) : 0.f; sum += e[j]; }
  #pragma unroll
  for (int o = 32; o; o >>= 1) sum += __shfl_xor(sum, o);

  const bool qvalid = mask[b * S_LEN + s] != 0;
  const float inv = (qvalid && sum > 0.f) ? 1.f / sum : 0.f;
  bf16x8_t o0, o1;
  #pragma unroll
  for (int j = 0; j < 8; ++j) { o0[j] = (bf16_t)(e[j] * inv); o1[j] = (bf16_t)(e[j+8] * inv); }
  *(bf16x8_t*)&row[t0] = o0;
  *(bf16x8_t*)&row[t0 + 8] = o1;
}

// ---------------- transpose (+cast to bf16): out[C][R] = in[R][C] ----------------
template<typename TIN>
__global__ void transpose_kernel(const TIN* __restrict__ in, bf16_t* __restrict__ out,
                                 int R, int C, long long sIn, long long sOut)
{
  __shared__ float tile[32][33];
  const long long zi = (long long)blockIdx.z * sIn;
  const long long zo = (long long)blockIdx.z * sOut;
  const int c0 = blockIdx.x * 32, r0 = blockIdx.y * 32;
  const int tx = threadIdx.x, ty = threadIdx.y;  // 32 x 8
  #pragma unroll
  for (int i = 0; i < 4; ++i) {
    int r = r0 + ty + i*8;
    tile[ty + i*8][tx] = (float)in[zi + (long long)r * C + c0 + tx];
  }
  __syncthreads();
  #pragma unroll
  for (int i = 0; i < 4; ++i) {
    int c = c0 + ty + i*8;
    out[zo + (long long)c * R + r0 + tx] = (bf16_t)tile[tx][ty + i*8];
  }
}

// ---------------- two-source f32 -> bf16 convert (out laid [a | b]) ----------------
__global__ void convert2_kernel(const float* __restrict__ a, const float* __restrict__ b,
                                bf16_t* __restrict__ out, long long n)
{
  long long i = (long long)blockIdx.x * blockDim.x + threadIdx.x;
  long long stride = (long long)gridDim.x * blockDim.x;
  for (; i < 2*n; i += stride)
    out[i] = (bf16_t)(i < n ? a[i] : b[i - n]);
}

// ---------------- diagnostic fill ----------------
__global__ void fill_kernel(float* __restrict__ out, long long n, float v)
{
  long long i = (long long)blockIdx.x * blockDim.x + threadIdx.x;
  long long stride = (long long)gridDim.x * blockDim.x;
  for (; i < n; i += stride) out[i] = v;
}

// ---------------- positions: pos = cumsum(mask) - 1 ----------------
__global__ void pos_kernel(const int* __restrict__ mask, float* __restrict__ pos)
{
  __shared__ float scn[S_LEN];
  const int b = blockIdx.x, t = threadIdx.x;
  scn[t] = (float)(mask[b * S_LEN + t] != 0);
  __syncthreads();
  for (int off = 1; off < S_LEN; off <<= 1) {
    float add = (t >= off) ? scn[t - off] : 0.f;
    __syncthreads();
    scn[t] += add;
    __syncthreads();
  }
  pos[b * S_LEN + t] = scn[t] - 1.0f;
}

// ---------------- embedding + positional encoding ----------------
__global__ void embed_kernel(const int* __restrict__ ids, const int* __restrict__ mask,
                             const float* __restrict__ pos, const float* __restrict__ emb,
                             float* __restrict__ x, bf16_t* __restrict__ xb)
{
  const int idx = blockIdx.x * 256 + threadIdx.x;
  const int i = idx & 255;
  const int bs = idx >> 8;
  const int id = ids[bs];
  const float m = (float)(mask[bs] != 0);
  const float p = pos[bs];
  const float dv = __expf(-(float)(2 * i) * (9.210340371976184f / (float)HD));
  const float sv = __sinf(p * dv) * m;
  const float e0 = emb[id * HD + 2*i], e1 = emb[id * HD + 2*i + 1];
  const float x0 = e0 + sv, x1 = e1 + sv;
  x[(long long)bs * HD + 2*i]     = x0;
  x[(long long)bs * HD + 2*i + 1] = x1;
  xb[(long long)bs * HD + 2*i]     = (bf16_t)x0;
  xb[(long long)bs * HD + 2*i + 1] = (bf16_t)x1;
}

// ---------------- layernorm, f32 partials (FF path) ----------------
__global__ void ln_kernel(float* __restrict__ x, const float* __restrict__ tparts,
                          int ns, long long pstride,
                          const float* __restrict__ bias,
                          const float* __restrict__ g, const float* __restrict__ b,
                          bf16_t* __restrict__ xb)
{
  const int lane = threadIdx.x & 63;
  const long long row = (long long)blockIdx.x * 4 + (threadIdx.x >> 6);
  const int e0 = lane * 8;
  const long long base = row * HD + e0;

  float4 xa = *(const float4*)&x[base];
  float4 xc = *(const float4*)&x[base + 4];
  float4 ba = *(const float4*)&bias[e0];
  float4 bc = *(const float4*)&bias[e0 + 4];
  float v[8] = {xa.x+ba.x, xa.y+ba.y, xa.z+ba.z, xa.w+ba.w,
                xc.x+bc.x, xc.y+bc.y, xc.z+bc.z, xc.w+bc.w};
  for (int i = 0; i < ns; ++i) {
    float4 p0 = *(const float4*)&tparts[i*pstride + base];
    float4 p1 = *(const float4*)&tparts[i*pstride + base + 4];
    v[0]+=p0.x; v[1]+=p0.y; v[2]+=p0.z; v[3]+=p0.w;
    v[4]+=p1.x; v[5]+=p1.y; v[6]+=p1.z; v[7]+=p1.w;
  }
  float s = 0.f;
  #pragma unroll
  for (int j = 0; j < 8; ++j) s += v[j];
  #pragma unroll
  for (int o = 32; o; o >>= 1) s += __shfl_xor(s, o);
  const float mu = s * (1.f / (float)HD);
  float q = 0.f;
  #pragma unroll
  for (int j = 0; j < 8; ++j) { v[j] -= mu; q += v[j]*v[j]; }
  #pragma unroll
  for (int o = 32; o; o >>= 1) q += __shfl_xor(q, o);
  const float inv = rsqrtf(q * (1.f / (float)HD) + 1e-5f);

  float4 ga4 = *(const float4*)&g[e0];
  float4 gc4 = *(const float4*)&g[e0 + 4];
  float4 bb4 = *(const float4*)&b[e0];
  float4 bd4 = *(const float4*)&b[e0 + 4];
  float y[8] = {v[0]*inv*ga4.x+bb4.x, v[1]*inv*ga4.y+bb4.y, v[2]*inv*ga4.z+bb4.z, v[3]*inv*ga4.w+bb4.w,
                v[4]*inv*gc4.x+bd4.x, v[5]*inv*gc4.y+bd4.y, v[6]*inv*gc4.z+bd4.z, v[7]*inv*gc4.w+bd4.w};
  *(float4*)&x[base]     = (float4){y[0],y[1],y[2],y[3]};
  *(float4*)&x[base + 4] = (float4){y[4],y[5],y[6],y[7]};
  bf16x8_t yb;
  #pragma unroll
  for (int j = 0; j < 8; ++j) yb[j] = (bf16_t)y[j];
  *(bf16x8_t*)&xb[base] = yb;
}

// ---------------- layernorm, 4x bf16 partials (attention path) ----------------
__global__ void lnb_kernel(float* __restrict__ x, const bf16_t* __restrict__ tparts,
                           long long pstride,
                           const float* __restrict__ bias,
                           const float* __restrict__ g, const float* __restrict__ b,
                           bf16_t* __restrict__ xb)
{
  const int lane = threadIdx.x & 63;
  const long long row = (long long)blockIdx.x * 4 + (threadIdx.x >> 6);
  const int e0 = lane * 8;
  const long long base = row * HD + e0;

  float4 xa = *(const float4*)&x[base];
  float4 xc = *(const float4*)&x[base + 4];
  float4 ba = *(const float4*)&bias[e0];
  float4 bc = *(const float4*)&bias[e0 + 4];
  float v[8] = {xa.x+ba.x, xa.y+ba.y, xa.z+ba.z, xa.w+ba.w,
                xc.x+bc.x, xc.y+bc.y, xc.z+bc.z, xc.w+bc.w};
  #pragma unroll
  for (int i = 0; i < 4; ++i) {
    bf16x8_t pp = *(const bf16x8_t*)&tparts[i*pstride + base];
    #pragma unroll
    for (int j = 0; j < 8; ++j) v[j] += (float)pp[j];
  }
  float s = 0.f;
  #pragma unroll
  for (int j = 0; j < 8; ++j) s += v[j];
  #pragma unroll
  for (int o = 32; o; o >>= 1) s += __shfl_xor(s, o);
  const float mu = s * (1.f / (float)HD);
  float q = 0.f;
  #pragma unroll
  for (int j = 0; j < 8; ++j) { v[j] -= mu; q += v[j]*v[j]; }
  #pragma unroll
  for (int o = 32; o; o >>= 1) q += __shfl_xor(q, o);
  const float inv = rsqrtf(q * (1.f / (float)HD) + 1e-5f);

  float4 ga4 = *(const float4*)&g[e0];
  float4 gc4 = *(const float4*)&g[e0 + 4];
  float4 bb4 = *(const float4*)&b[e0];
  float4 bd4 = *(const float4*)&b[e0 + 4];
  float y[8] = {v[0]*inv*ga4.x+bb4.x, v[1]*inv*ga4.y+bb4.y, v[2]*inv*ga4.z+bb4.z, v[3]*inv*ga4.w+bb4.w,
                v[4]*inv*gc4.x+bd4.x, v[5]*inv*gc4.y+bd4.y, v[6]*inv*gc4.z+bd4.z, v[7]*inv*gc4.w+bd4.w};
  *(float4*)&x[base]     = (float4){y[0],y[1],y[2],y[3]};
  *(float4*)&x[base + 4] = (float4){y[4],y[5],y[6],y[7]};
  bf16x8_t yb;
  #pragma unroll
  for (int j = 0; j < 8; ++j) yb[j] = (bf16_t)y[j];
  *(bf16x8_t*)&xb[base] = yb;
}

extern "C" void kernel_launch(void* const* d_in, const int* in_sizes, int n_in,
                              void* d_out, int out_size, void* d_ws, size_t ws_size,
                              hipStream_t stream)
{
  (void)in_sizes; (void)n_in;
  const int*   ids   = (const int*)d_in[0];
  const int*   amask = (const int*)d_in[1];
  const float* emb   = (const float*)d_in[2];
  const float* wq    = (const float*)d_in[3];
  const float* wk    = (const float*)d_in[4];
  const float* wv    = (const float*)d_in[5];
  const float* wo_w  = (const float*)d_in[6];
  const float* wo_b  = (const float*)d_in[7];
  const float* ln1_g = (const float*)d_in[8];
  const float* ln1_b = (const float*)d_in[9];
  const float* ff1_w = (const float*)d_in[10];
  const float* ff1_b = (const float*)d_in[11];
  const float* ff2_w = (const float*)d_in[12];
  const float* ff2_b = (const float*)d_in[13];
  const float* ln2_g = (const float*)d_in[14];
  const float* ln2_b = (const float*)d_in[15];
  const float* lm_w  = (const float*)d_in[16];

  const long long MROW = (long long)BATCH * S_LEN;   // 8192
  const size_t MBc = 1ull << 20;
  char* p = (char*)d_ws;
  auto alloc = [&](size_t bytes) { char* r = p; p += (bytes + 255) & ~(size_t)255; return r; };

  // persistent (~81 MB): all-layer weights prepped ONCE upfront (r18)
  float*  x     = (float*) alloc(MROW * HD * 4);                // 16 MB
  bf16_t* xb    = (bf16_t*)alloc(MROW * HD * 2);                // 8 MB
  bf16_t* ob    = (bf16_t*)alloc(4LL * MROW * HD * 2);          // 32 MB: 4 head-partials
  bf16_t* Gt3   = (bf16_t*)alloc(12LL * HD * HD * 2);           // 6 MB  Gt[l][h][n][a]
  bf16_t* UT3   = (bf16_t*)alloc(12LL * HD * HD * 2);           // 6 MB  UT[l][h][f][c]
  bf16_t* wffa  = (bf16_t*)alloc(6LL * FFD * HD * 2);           // 12 MB [ff1 l0..2 | ff2 l0..2]
  bf16_t* lmT   = (bf16_t*)alloc((long long)NTOK * HD * 2);
  float*  pos   = (float*) alloc(MROW * 4);

  const size_t used = (size_t)(p - (char*)d_ws);
  const size_t rem  = ws_size > used ? ws_size - used : 0;

  // attn region: P*(y 1MB + uT 1MB) + P*2MB scores;  FF region SK*16+32 MB (aliased)
  int P = 0, SK = 2;
  if      (rem >= 128 * MBc) { P = 32; SK = 4; }  // attn 128 MB, FF 96 MB
  else if (rem >= 64 * MBc)  { P = 8;  SK = 2; }  // attn 32 MB, FF 64 MB
  if (P == 0) {
    fill_kernel<<<1024, 256, 0, stream>>>((float*)d_out, (long long)out_size,
                                          (float)(ws_size >> 20));
    return;
  }

  char* A = p;
  const long long pairE = (long long)S_LEN * HD;
  bf16_t* qc  = (bf16_t*)A;                        // y per pair
  bf16_t* uTc = qc  + (long long)P * pairE;        // uT per pair (u = x@U, U=Wv@Wo)
  bf16_t* scb = uTc + (long long)P * pairE;        // bf16 scores, softmax in-place
  float*  tmp = (float*)A;                          // FF phase aliases (SK partials)
  bf16_t* ffb = (bf16_t*)(A + (size_t)SK * 16 * MBc);
  // prep scratch (in A; dead once layer loop starts): [wq|wk] 24MB, wv 6MB, woT 6MB
  bf16_t* wqkb = (bf16_t*)A;                        // 24 MB
  bf16_t* wvb  = wqkb + 24LL * HD * HD;             // 6 MB
  bf16_t* woTa = wvb  + 12LL * HD * HD;             // 6 MB (3x [HD][FFD])

  const dim3 tb(32, 8);
  // -------- one-time weight prep (batched over all 3 layers) --------
  transpose_kernel<float><<<dim3(4,16,1), tb, 0, stream>>>(lm_w, lmT, HD, NTOK, 0, 0);
  convert2_kernel<<<4096, 256, 0, stream>>>(wq, wk, wqkb, 12LL*HD*HD);
  convert2_kernel<<<2048, 256, 0, stream>>>(wv, wv + 6LL*HD*HD, wvb, 6LL*HD*HD);
  transpose_kernel<float><<<dim3(16,64,3), tb, 0, stream>>>(
    wo_w, woTa, FFD, HD, (long long)FFD*HD, (long long)HD*FFD);
  convert2_kernel<<<4096, 256, 0, stream>>>(ff1_w, ff2_w, wffa, 3LL*FFD*HD);
  // Gt[l*4+h] = Wk[l,h] @ Wq[l,h]^T  (z=12; contiguous strides across l,h)
  gemm_bt_kernel<true,false,false,false,false><<<dim3(4,4,12),256,0,stream>>>(
    wqkb + 12LL*HD*HD, wqkb, nullptr, Gt3,
    HD, HD, HD, HD, HD, HD,
    (long long)HD*HD, (long long)HD*HD, 0, 0,
    30, 0, (long long)HD*HD,
    30, 0, 1.f);
  // UT[l*4+h] = (Wv[l,h] @ Wo[l])^T : A=woT[l] col block h, B=wv[l,h] (per-layer launch)
  for (int l = 0; l < NBLK; ++l)
    gemm_bt_kernel<true,false,false,false,false><<<dim3(4,4,4),256,0,stream>>>(
      woTa + (long long)l*HD*FFD, wvb + (long long)l*4*HD*HD, nullptr,
      UT3 + (long long)l*4*HD*HD,
      HD, HD, HD, FFD, HD, HD,
      512, (long long)HD*HD, 0, 0,
      30, 0, (long long)HD*HD,
      30, 0, 1.f);

  pos_kernel<<<BATCH, S_LEN, 0, stream>>>(amask, pos);
  embed_kernel<<<8192, 256, 0, stream>>>(ids, amask, pos, emb, x, xb);

  const int nch = 32 / P;
  const int bpc = P / NHEAD;

  for (int l = 0; l < NBLK; ++l) {
    const bf16_t* Gt  = Gt3 + (long long)l*4*HD*HD;
    const bf16_t* UT  = UT3 + (long long)l*4*HD*HD;
    const bf16_t* wf1 = wffa + (long long)l*FFD*HD;
    const bf16_t* wf2 = wffa + 3LL*FFD*HD + (long long)l*HD*FFD;

    for (int c = 0; c < nch; ++c) {
      const int b0 = c * bpc;
      const int pair0 = b0 * NHEAD;
      const int Mch = bpc * S_LEN;

      // y = x @ G per head (z = head): replaces q AND k projections
      gemm256_kernel<true,false,false,false,false,false><<<dim3(Mch/256,2,4),512,0,stream>>>(
        xb + (long long)b0*S_LEN*HD, Gt, nullptr, qc, Mch, HD, HD, HD, HD, HD,
        0, (long long)HD*HD, 0, 0,
        2, 0, pairE,
        10, (long long)NHEAD*pairE, 1.f);

      // uT[pair][f][t] = sum_c UT[h][f][c] * xb[b,t,c]   (u = x@U; PV B-operand)
      gemm256_kernel<true,false,false,false,false,false><<<dim3(8,4,bpc),512,0,stream>>>(
        UT, xb + (long long)b0*S_LEN*HD, nullptr, uTc,
        2048, S_LEN, HD, HD, HD, S_LEN,
        0, (long long)S_LEN*HD, 0, 0,
        0, (long long)NHEAD*HD*S_LEN, 0,
        9, (long long)HD*S_LEN, 1.f);

      // scores = y @ xb^T / sqrt(512) -> bf16 scb. 128^2 tiles (CSKIP causal),
      // fine-grain backfill (r16). B shared per 4 heads.
      gemm_bt_kernel<true,false,false,true,false><<<dim3(8,8,P),256,0,stream>>>(
        qc, xb + (long long)b0*S_LEN*HD, nullptr, scb,
        S_LEN, S_LEN, HD, HD, HD, S_LEN,
        pairE, (long long)S_LEN*HD, 2, 0,
        30, 0, (long long)S_LEN*S_LEN,
        30, 0, 0.044194173824159216f);
      softmax_kernel<<<dim3(S_LEN/4,P),256,0,stream>>>(scb, amask, pair0);
      // head-partial mh_h = P~_h @ u_h  -> ob[h][b*1024+s][*] bf16 (z = b*4+h)
      gemm256_kernel<true,false,false,false,true,false><<<dim3(4,2,P),512,0,stream>>>(
        scb, uTc, nullptr, ob,
        S_LEN, HD, S_LEN, S_LEN, S_LEN, HD,
        (long long)S_LEN*S_LEN, (long long)HD*S_LEN, 0, 0,
        2, (long long)S_LEN*HD, (long long)MROW*HD,
        30, 0, 1.f);
    }

    // x = LN(x + sum_h ob[h] + wo_b)  (wo GEMM folded into U)
    lnb_kernel<<<2048,256,0,stream>>>(x, ob, (long long)MROW*HD,
                                      wo_b + l*HD, ln1_g + l*HD, ln1_b + l*HD, xb);

    // ff1: relu(xb @ ff1^T + b1) -> ffb (bf16)
    gemm256_kernel<true,true,true,false,false,false><<<dim3(32,8,1),512,0,stream>>>(
      xb, wf1, ff1_b + l*FFD, ffb,
      (int)MROW, FFD, HD, HD, HD, FFD,
      0, 0, 0, 0, 30, 0, 0, 30, 0, 1.f);
    // ff2 (split-K=SK)
    gemm256_kernel<false,false,false,false,false,false><<<dim3(32,2,SK),512,0,stream>>>(
      ffb, wf2, nullptr, tmp,
      (int)MROW, HD, FFD/SK, FFD, FFD, HD,
      FFD/SK, FFD/SK, 0, 0,
      0, (long long)MROW*HD, 0,
      30, 0, 1.f);
    ln_kernel<<<2048,256,0,stream>>>(x, tmp, SK, (long long)MROW*HD,
                                     ff2_b + l*HD, ln2_g + l*HD, ln2_b + l*HD, xb);
  }

  // lm head -> d_out (f32), N=128 -> 128-tile kernel
  gemm_bt_kernel<false,false,false,false,false><<<dim3(64,1,1),256,0,stream>>>(
    xb, lmT, nullptr, (float*)d_out,
    (int)MROW, NTOK, HD, HD, HD, NTOK,
    0, 0, 0, 0, 30, 0, 0, 30, 0, 1.f);
}

// Round 21
// 749.462 us; speedup vs baseline: 1.0699x; 1.0258x over previous
//
#include <hip/hip_runtime.h>
#include <hip/hip_bf16.h>

#define S_LEN 1024
#define BATCH 8
#define HD 512
#define FFD 2048
#define NHEAD 4
#define NBLK 3
#define NTOK 128

typedef __bf16 bf16_t;
typedef __bf16 bf16x4_t __attribute__((ext_vector_type(4)));
typedef __bf16 bf16x8_t __attribute__((ext_vector_type(8)));
typedef float f32x4_t __attribute__((ext_vector_type(4)));

typedef __attribute__((address_space(3))) uint32_t lds_u32;
typedef __attribute__((address_space(1))) uint32_t glb_u32;

// ---- LDS fragment read: NI frags of 16 rows from row0, XOR-swizzled chunks ----
template<int NI>
__device__ __forceinline__ void ldsread(const bf16_t* __restrict__ buf, int row0,
                                        int fr, int fg, int sw, bf16x8_t (&dst)[NI][2]) {
  #pragma unroll
  for (int i = 0; i < NI; ++i)
    #pragma unroll
    for (int ks = 0; ks < 2; ++ks)
      dst[i][ks] = *(const bf16x8_t*)&buf[(row0 + i*16 + fr)*64 + (((ks*4 + fg) ^ sw) << 3)];
}

// ---- one C-quadrant x K=64: 16 MFMA ----
template<int IB, int JB>
__device__ __forceinline__ void mquad(f32x4_t (&acc)[8][4],
                                      const bf16x8_t (&af)[4][2], const bf16x8_t (&bf)[2][2]) {
  #pragma unroll
  for (int ks = 0; ks < 2; ++ks)
    #pragma unroll
    for (int i = 0; i < 4; ++i)
      #pragma unroll
      for (int j = 0; j < 2; ++j)
        acc[IB+i][JB+j] = __builtin_amdgcn_mfma_f32_16x16x32_bf16(af[i][ks], bf[j][ks], acc[IB+i][JB+j], 0, 0, 0);
}

// ================= 256x256 GEMM (r16 configuration, 765us best — frozen) =================
// DB: r7 2-barrier/K-tile, 2-deep counted-vmcnt prefetch, 128KiB LDS, 1 blk/CU.
// launch_bounds (512,2): VGPR cap 128 (r8: arg 4 -> 64 VGPR -> acc spilled).
// r13/r17/r19: epilogue or pipeline template edits perturb codegen (rule #19) — frozen.
// TRI: blockIdx.x = lower-triangle tile index. bshift: B shared across 2^bshift z.
template<bool OUT_BF16, bool BIAS, bool RELU, bool TRI, bool CKLIM, bool NORM>
__global__ __launch_bounds__(512, 2)
void gemm256_kernel(const bf16_t* __restrict__ A,
                    const bf16_t* __restrict__ Bt,
                    const float* __restrict__ bias,
                    void* __restrict__ Cv,
                    int M, int N, int K,
                    int lda, int ldb, int ldc,
                    long long sA, long long sB, int bshift, long long sBias,
                    int zshift, long long sC_hi, long long sC_lo,
                    int msub_shift, long long msub_stride,
                    float alpha)
{
  const int zb = blockIdx.z;
  int m0, n0;
  if (TRI) {
    const int idx = blockIdx.x;
    int mi = (int)((sqrtf(8.f * idx + 1.f) - 1.f) * 0.5f);
    while ((mi + 1) * (mi + 2) / 2 <= idx) ++mi;
    while (mi * (mi + 1) / 2 > idx) --mi;
    m0 = mi * 256;
    n0 = (idx - mi * (mi + 1) / 2) * 256;
  } else {
    m0 = blockIdx.x * 256;
    n0 = blockIdx.y * 256;
  }
  int kend = K;
  if (CKLIM) { int ke = m0 + 256; kend = ke < K ? ke : K; }
  const int nt = kend >> 6;

  const bf16_t* Az = A + (long long)zb * sA;
  const bf16_t* Bz = Bt + (long long)(zb >> bshift) * sB;
  const long long coff = ((long long)(zb >> zshift)) * sC_hi
                       + ((long long)(zb & ((1 << zshift) - 1))) * sC_lo;

  __shared__ __align__(16) bf16_t As[2][256 * 64];
  __shared__ __align__(16) bf16_t Bs[2][256 * 64];

  const int tid = threadIdx.x;          // 0..511
  const int lane = tid & 63;
  const int w = tid >> 6;               // 0..7
  const int wm = (w >> 2) * 128;        // 0,128
  const int wn = (w & 3) * 64;          // 0,64,128,192
  const int fr = lane & 15;
  const int fg = lane >> 4;
  const int sw = fr & 7;

  const int srow = tid >> 3;            // 0..63
  const int scol8 = tid & 7;
  const int gswz = ((scol8 ^ (srow & 7)) << 3);

  f32x4_t acc[8][4];
  #pragma unroll
  for (int i = 0; i < 8; ++i)
    #pragma unroll
    for (int j = 0; j < 4; ++j)
      acc[i][j] = (f32x4_t){0.f, 0.f, 0.f, 0.f};

  const bf16_t* gA0 = Az + (long long)(m0 + srow) * lda + gswz;
  const bf16_t* gB0 = Bz + (long long)(n0 + srow) * ldb + gswz;

  // stage one 128x64 half-tile (2 global_load_lds/thread). h:0=A0,1=A1,2=B0,3=B1
  auto stage_half = [&](int buf, int kt, int h) {
    if (h < 2) {
      const bf16_t* g = gA0 + (long long)(h * 128) * lda + (kt << 6);
      bf16_t* l = &As[buf][(h*128 + srow) * 64 + (scol8 << 3)];
      __builtin_amdgcn_global_load_lds((const glb_u32*)g, (lds_u32*)l, 16, 0, 0);
      __builtin_amdgcn_global_load_lds((const glb_u32*)(g + 64LL*lda), (lds_u32*)(l + 64*64), 16, 0, 0);
    } else {
      const int hh = h - 2;
      const bf16_t* g = gB0 + (long long)(hh * 128) * ldb + (kt << 6);
      bf16_t* l = &Bs[buf][(hh*128 + srow) * 64 + (scol8 << 3)];
      __builtin_amdgcn_global_load_lds((const glb_u32*)g, (lds_u32*)l, 16, 0, 0);
      __builtin_amdgcn_global_load_lds((const glb_u32*)(g + 64LL*ldb), (lds_u32*)(l + 64*64), 16, 0, 0);
    }
  };

  // prologue: full t0 + A-halves of t1; wait t0 landed (A(t1)'s 4 loads in flight)
  stage_half(0, 0, 0); stage_half(0, 0, 1); stage_half(0, 0, 2); stage_half(0, 0, 3);
  if (nt > 1) { stage_half(1, 1, 0); stage_half(1, 1, 1); }
  if (nt > 1) asm volatile("s_waitcnt vmcnt(4)" ::: "memory");
  else        asm volatile("s_waitcnt vmcnt(0)" ::: "memory");
  __builtin_amdgcn_s_barrier();
  __builtin_amdgcn_sched_barrier(0);

  for (int t = 0; t < nt; ++t) {
    const int cur = t & 1;
    const bf16_t* Ac = &As[cur][0];
    const bf16_t* Bc = &Bs[cur][0];
    bf16x8_t a0[4][2], a1[4][2], b0[2][2], b1[2][2];

    // region 1: all LDS reads of tile t + B-stages of t+1 (other buffer)
    ldsread<4>(Ac, wm, fr, fg, sw, a0);
    ldsread<2>(Bc, wn, fr, fg, sw, b0);
    if (t + 1 < nt) stage_half(cur ^ 1, t + 1, 2);
    mquad<0, 0>(acc, a0, b0);
    ldsread<4>(Ac, wm + 64, fr, fg, sw, a1);
    ldsread<2>(Bc, wn + 32, fr, fg, sw, b1);
    if (t + 1 < nt) stage_half(cur ^ 1, t + 1, 3);
    mquad<4, 2>(acc, a1, b1);

    __builtin_amdgcn_s_barrier();        // all reads of buf cur consumed
    __builtin_amdgcn_sched_barrier(0);

    // region 2: register-only quads + A-stages of t+2 (into buf cur)
    if (t + 2 < nt) stage_half(cur, t + 2, 0);
    mquad<0, 2>(acc, a0, b1);
    if (t + 2 < nt) {
      stage_half(cur, t + 2, 1);
      asm volatile("s_waitcnt vmcnt(4)" ::: "memory");   // tile t+1 fully landed
    } else {
      asm volatile("s_waitcnt vmcnt(0)" ::: "memory");
    }
    mquad<4, 0>(acc, a1, b0);

    __builtin_amdgcn_s_barrier();        // collective: t+1 data visible to all
    __builtin_amdgcn_sched_barrier(0);
  }

  #pragma unroll
  for (int i = 0; i < 8; ++i) {
    #pragma unroll
    for (int e = 0; e < 4; ++e) {
      const int row = m0 + wm + i*16 + fg*4 + e;
      const long long ro = coff
        + ((long long)(row >> msub_shift)) * msub_stride
        + (long long)(row & ((1 << msub_shift) - 1)) * (long long)ldc;
      float rn = 1.f;
      if (NORM) rn = bias[(long long)zb * sBias + row];
      #pragma unroll
      for (int j = 0; j < 4; ++j) {
        const int col = n0 + wn + j*16 + fr;
        float v = acc[i][j][e] * alpha;
        if (BIAS) v += bias[(long long)zb * sBias + col];
        if (NORM) v *= rn;
        if (RELU) v = v > 0.f ? v : 0.f;
        if (OUT_BF16) ((bf16_t*)Cv)[ro + col] = (bf16_t)v;
        else          ((float*)Cv)[ro + col]  = v;
      }
    }
  }
}

// ================= 128x128 m97-style GEMM (scores, G-gemm, UT-gemm, lm head) ============
// (256,2): ~100 VGPR + 32KB LDS -> ~5 resident blocks/CU (fine-grain backfill).
// CSKIP: causal tile skip. bshift: B shared across 2^bshift z (scores: 4 heads/batch).
template<bool OUT_BF16, bool BIAS, bool RELU, bool CSKIP, bool CKLIM>
__global__ __launch_bounds__(256, 2)
void gemm_bt_kernel(const bf16_t* __restrict__ A,
                    const bf16_t* __restrict__ Bt,
                    const float* __restrict__ bias,
                    void* __restrict__ Cv,
                    int M, int N, int K,
                    int lda, int ldb, int ldc,
                    long long sA, long long sB, int bshift, long long sBias,
                    int zshift, long long sC_hi, long long sC_lo,
                    int msub_shift, long long msub_stride,
                    float alpha)
{
  const int zb = blockIdx.z;
  const int m0 = blockIdx.x * 128;
  const int n0 = blockIdx.y * 128;
  if (CSKIP && n0 > m0 + 127) return;
  int kend = K;
  if (CKLIM) { int ke = m0 + 128; kend = ke < K ? ke : K; }

  const bf16_t* Az = A + (long long)zb * sA;
  const bf16_t* Bz = Bt + (long long)(zb >> bshift) * sB;
  const long long coff = ((long long)(zb >> zshift)) * sC_hi
                       + ((long long)(zb & ((1 << zshift) - 1))) * sC_lo;

  __shared__ __align__(16) bf16_t As[128 * 64];
  __shared__ __align__(16) bf16_t Bs[128 * 64];

  const int tid = threadIdx.x;
  const int wv = tid >> 6;
  const int lane = tid & 63;
  const int wm = (wv >> 1) * 64;
  const int wn = (wv & 1) * 64;
  const int fr = lane & 15;
  const int fg = lane >> 4;
  const int sw = fr & 7;

  f32x4_t acc[4][4];
  #pragma unroll
  for (int i = 0; i < 4; ++i)
    #pragma unroll
    for (int j = 0; j < 4; ++j)
      acc[i][j] = (f32x4_t){0.f, 0.f, 0.f, 0.f};

  const bf16_t* ga = Az + (long long)(m0 + (wv << 5) + (lane >> 3)) * lda
                   + (((lane & 7) ^ (lane >> 3)) << 3);
  const bf16_t* gb = Bz + (long long)(n0 + (wv << 5) + (lane >> 3)) * ldb
                   + (((lane & 7) ^ (lane >> 3)) << 3);

  for (int k0 = 0; k0 < kend; k0 += 64) {
    #pragma unroll
    for (int s = 0; s < 4; ++s) {
      __builtin_amdgcn_global_load_lds(
        (const glb_u32*)(ga + (long long)s * 8 * lda + k0),
        (lds_u32*)(As + (wv * 4 + s) * 512), 16, 0, 0);
      __builtin_amdgcn_global_load_lds(
        (const glb_u32*)(gb + (long long)s * 8 * ldb + k0),
        (lds_u32*)(Bs + (wv * 4 + s) * 512), 16, 0, 0);
    }
    __syncthreads();
    #pragma unroll
    for (int kc = 0; kc < 2; ++kc) {
      const int ca = ((kc * 4 + fg) ^ sw) << 3;
      bf16x8_t af[4], bfr[4];
      #pragma unroll
      for (int i = 0; i < 4; ++i)
        af[i] = *(const bf16x8_t*)&As[(wm + i*16 + fr) * 64 + ca];
      #pragma unroll
      for (int j = 0; j < 4; ++j)
        bfr[j] = *(const bf16x8_t*)&Bs[(wn + j*16 + fr) * 64 + ca];
      #pragma unroll
      for (int i = 0; i < 4; ++i)
        #pragma unroll
        for (int j = 0; j < 4; ++j)
          acc[i][j] = __builtin_amdgcn_mfma_f32_16x16x32_bf16(af[i], bfr[j], acc[i][j], 0, 0, 0);
    }
    __syncthreads();
  }

  #pragma unroll
  for (int i = 0; i < 4; ++i) {
    #pragma unroll
    for (int e = 0; e < 4; ++e) {
      const int row = m0 + wm + i*16 + fg*4 + e;
      const long long ro = coff
        + ((long long)(row >> msub_shift)) * msub_stride
        + (long long)(row & ((1 << msub_shift) - 1)) * (long long)ldc;
      #pragma unroll
      for (int j = 0; j < 4; ++j) {
        const int col = n0 + wn + j*16 + fr;
        float v = acc[i][j][e] * alpha;
        if (BIAS) v += bias[(long long)zb * sBias + col];
        if (RELU) v = v > 0.f ? v : 0.f;
        if (OUT_BF16) ((bf16_t*)Cv)[ro + col] = (bf16_t)v;
        else          ((float*)Cv)[ro + col]  = v;
      }
    }
  }
}

// ---------------- softmax: ONE WAVE PER ROW, bf16 in-place, pure shfl reduce ----------------
__global__ void softmax_kernel(bf16_t* __restrict__ scP,
                               const int* __restrict__ mask, int pair0)
{
  const int lane = threadIdx.x & 63;
  const int s = blockIdx.x * 4 + (threadIdx.x >> 6);
  const int pz = blockIdx.y;
  const int b = (pair0 + pz) >> 2;
  bf16_t* row = scP + ((long long)pz * S_LEN + s) * S_LEN;
  const int t0 = lane * 16;

  bf16x8_t r0 = *(const bf16x8_t*)&row[t0];
  bf16x8_t r1 = *(const bf16x8_t*)&row[t0 + 8];
  int4 m4[4];
  #pragma unroll
  for (int q = 0; q < 4; ++q) m4[q] = *(const int4*)&mask[b * S_LEN + t0 + q*4];
  const int* mm = (const int*)m4;

  float v[16]; bool ok[16];
  #pragma unroll
  for (int j = 0; j < 16; ++j) {
    const int t = t0 + j;
    ok[j] = (t <= s) && (mm[j] != 0);
    float raw = (j < 8) ? (float)r0[j] : (float)r1[j - 8];
    v[j] = ok[j] ? raw : -INFINITY;
  }
  float mx = v[0];
  #pragma unroll
  for (int j = 1; j < 16; ++j) mx = fmaxf(mx, v[j]);
  #pragma unroll
  for (int o = 32; o; o >>= 1) mx = fmaxf(mx, __shfl_xor(mx, o));

  float e[16]; float sum = 0.f;
  #pragma unroll
  for (int j = 0; j < 16; ++j) { e[j] = ok[j] ? __expf(v[j] - mx) : 0.f; sum += e[j]; }
  #pragma unroll
  for (int o = 32; o; o >>= 1) sum += __shfl_xor(sum, o);

  const bool qvalid = mask[b * S_LEN + s] != 0;
  const float inv = (qvalid && sum > 0.f) ? 1.f / sum : 0.f;
  bf16x8_t o0, o1;
  #pragma unroll
  for (int j = 0; j < 8; ++j) { o0[j] = (bf16_t)(e[j] * inv); o1[j] = (bf16_t)(e[j+8] * inv); }
  *(bf16x8_t*)&row[t0] = o0;
  *(bf16x8_t*)&row[t0 + 8] = o1;
}

// ---------------- transpose (+cast to bf16): out[C][R] = in[R][C] ----------------
template<typename TIN>
__global__ void transpose_kernel(const TIN* __restrict__ in, bf16_t* __restrict__ out,
                                 int R, int C, long long sIn, long long sOut)
{
  __shared__ float tile[32][33];
  const long long zi = (long long)blockIdx.z * sIn;
  const long long zo = (long long)blockIdx.z * sOut;
  const int c0 = blockIdx.x * 32, r0 = blockIdx.y * 32;
  const int tx = threadIdx.x, ty = threadIdx.y;  // 32 x 8
  #pragma unroll
  for (int i = 0; i < 4; ++i) {
    int r = r0 + ty + i*8;
    tile[ty + i*8][tx] = (float)in[zi + (long long)r * C + c0 + tx];
  }
  __syncthreads();
  #pragma unroll
  for (int i = 0; i < 4; ++i) {
    int c = c0 + ty + i*8;
    out[zo + (long long)c * R + r0 + tx] = (bf16_t)tile[tx][ty + i*8];
  }
}

// ---------------- two-source f32 -> bf16 convert (out laid [a | b]) ----------------
__global__ void convert2_kernel(const float* __restrict__ a, const float* __restrict__ b,
                                bf16_t* __restrict__ out, long long n)
{
  long long i = (long long)blockIdx.x * blockDim.x + threadIdx.x;
  long long stride = (long long)gridDim.x * blockDim.x;
  for (; i < 2*n; i += stride)
    out[i] = (bf16_t)(i < n ? a[i] : b[i - n]);
}

// ---------------- diagnostic fill ----------------
__global__ void fill_kernel(float* __restrict__ out, long long n, float v)
{
  long long i = (long long)blockIdx.x * blockDim.x + threadIdx.x;
  long long stride = (long long)gridDim.x * blockDim.x;
  for (; i < n; i += stride) out[i] = v;
}

// ---------------- positions: pos = cumsum(mask) - 1 ----------------
__global__ void pos_kernel(const int* __restrict__ mask, float* __restrict__ pos)
{
  __shared__ float scn[S_LEN];
  const int b = blockIdx.x, t = threadIdx.x;
  scn[t] = (float)(mask[b * S_LEN + t] != 0);
  __syncthreads();
  for (int off = 1; off < S_LEN; off <<= 1) {
    float add = (t >= off) ? scn[t - off] : 0.f;
    __syncthreads();
    scn[t] += add;
    __syncthreads();
  }
  pos[b * S_LEN + t] = scn[t] - 1.0f;
}

// ---------------- embedding + positional encoding ----------------
__global__ void embed_kernel(const int* __restrict__ ids, const int* __restrict__ mask,
                             const float* __restrict__ pos, const float* __restrict__ emb,
                             float* __restrict__ x, bf16_t* __restrict__ xb)
{
  const int idx = blockIdx.x * 256 + threadIdx.x;
  const int i = idx & 255;
  const int bs = idx >> 8;
  const int id = ids[bs];
  const float m = (float)(mask[bs] != 0);
  const float p = pos[bs];
  const float dv = __expf(-(float)(2 * i) * (9.210340371976184f / (float)HD));
  const float sv = __sinf(p * dv) * m;
  const float e0 = emb[id * HD + 2*i], e1 = emb[id * HD + 2*i + 1];
  const float x0 = e0 + sv, x1 = e1 + sv;
  x[(long long)bs * HD + 2*i]     = x0;
  x[(long long)bs * HD + 2*i + 1] = x1;
  xb[(long long)bs * HD + 2*i]     = (bf16_t)x0;
  xb[(long long)bs * HD + 2*i + 1] = (bf16_t)x1;
}

// ---------------- layernorm, 4x bf16 partials ----------------
__global__ void lnb_kernel(float* __restrict__ x, const bf16_t* __restrict__ tparts,
                           long long pstride,
                           const float* __restrict__ bias,
                           const float* __restrict__ g, const float* __restrict__ b,
                           bf16_t* __restrict__ xb)
{
  const int lane = threadIdx.x & 63;
  const long long row = (long long)blockIdx.x * 4 + (threadIdx.x >> 6);
  const int e0 = lane * 8;
  const long long base = row * HD + e0;

  float4 xa = *(const float4*)&x[base];
  float4 xc = *(const float4*)&x[base + 4];
  float4 ba = *(const float4*)&bias[e0];
  float4 bc = *(const float4*)&bias[e0 + 4];
  float v[8] = {xa.x+ba.x, xa.y+ba.y, xa.z+ba.z, xa.w+ba.w,
                xc.x+bc.x, xc.y+bc.y, xc.z+bc.z, xc.w+bc.w};
  #pragma unroll
  for (int i = 0; i < 4; ++i) {
    bf16x8_t pp = *(const bf16x8_t*)&tparts[i*pstride + base];
    #pragma unroll
    for (int j = 0; j < 8; ++j) v[j] += (float)pp[j];
  }
  float s = 0.f;
  #pragma unroll
  for (int j = 0; j < 8; ++j) s += v[j];
  #pragma unroll
  for (int o = 32; o; o >>= 1) s += __shfl_xor(s, o);
  const float mu = s * (1.f / (float)HD);
  float q = 0.f;
  #pragma unroll
  for (int j = 0; j < 8; ++j) { v[j] -= mu; q += v[j]*v[j]; }
  #pragma unroll
  for (int o = 32; o; o >>= 1) q += __shfl_xor(q, o);
  const float inv = rsqrtf(q * (1.f / (float)HD) + 1e-5f);

  float4 ga4 = *(const float4*)&g[e0];
  float4 gc4 = *(const float4*)&g[e0 + 4];
  float4 bb4 = *(const float4*)&b[e0];
  float4 bd4 = *(const float4*)&b[e0 + 4];
  float y[8] = {v[0]*inv*ga4.x+bb4.x, v[1]*inv*ga4.y+bb4.y, v[2]*inv*ga4.z+bb4.z, v[3]*inv*ga4.w+bb4.w,
                v[4]*inv*gc4.x+bd4.x, v[5]*inv*gc4.y+bd4.y, v[6]*inv*gc4.z+bd4.z, v[7]*inv*gc4.w+bd4.w};
  *(float4*)&x[base]     = (float4){y[0],y[1],y[2],y[3]};
  *(float4*)&x[base + 4] = (float4){y[4],y[5],y[6],y[7]};
  bf16x8_t yb;
  #pragma unroll
  for (int j = 0; j < 8; ++j) yb[j] = (bf16_t)y[j];
  *(bf16x8_t*)&xb[base] = yb;
}

extern "C" void kernel_launch(void* const* d_in, const int* in_sizes, int n_in,
                              void* d_out, int out_size, void* d_ws, size_t ws_size,
                              hipStream_t stream)
{
  (void)in_sizes; (void)n_in;
  const int*   ids   = (const int*)d_in[0];
  const int*   amask = (const int*)d_in[1];
  const float* emb   = (const float*)d_in[2];
  const float* wq    = (const float*)d_in[3];
  const float* wk    = (const float*)d_in[4];
  const float* wv    = (const float*)d_in[5];
  const float* wo_w  = (const float*)d_in[6];
  const float* wo_b  = (const float*)d_in[7];
  const float* ln1_g = (const float*)d_in[8];
  const float* ln1_b = (const float*)d_in[9];
  const float* ff1_w = (const float*)d_in[10];
  const float* ff1_b = (const float*)d_in[11];
  const float* ff2_w = (const float*)d_in[12];
  const float* ff2_b = (const float*)d_in[13];
  const float* ln2_g = (const float*)d_in[14];
  const float* ln2_b = (const float*)d_in[15];
  const float* lm_w  = (const float*)d_in[16];

  const long long MROW = (long long)BATCH * S_LEN;   // 8192
  const size_t MBc = 1ull << 20;
  char* p = (char*)d_ws;
  auto alloc = [&](size_t bytes) { char* r = p; p += (bytes + 255) & ~(size_t)255; return r; };

  // persistent (~81 MB): all-layer weights prepped ONCE upfront (r18)
  float*  x     = (float*) alloc(MROW * HD * 4);                // 16 MB
  bf16_t* xb    = (bf16_t*)alloc(MROW * HD * 2);                // 8 MB
  bf16_t* ob    = (bf16_t*)alloc(4LL * MROW * HD * 2);          // 32 MB: 4 bf16 partials
  bf16_t* Gt3   = (bf16_t*)alloc(12LL * HD * HD * 2);           // 6 MB  Gt[l][h][n][a]
  bf16_t* UT3   = (bf16_t*)alloc(12LL * HD * HD * 2);           // 6 MB  UT[l][h][f][c]
  bf16_t* wffa  = (bf16_t*)alloc(6LL * FFD * HD * 2);           // 12 MB [ff1 l0..2 | ff2 l0..2]
  bf16_t* lmT   = (bf16_t*)alloc((long long)NTOK * HD * 2);
  float*  pos   = (float*) alloc(MROW * 4);

  const size_t used = (size_t)(p - (char*)d_ws);
  const size_t rem  = ws_size > used ? ws_size - used : 0;

  // attn region: P*(y 1MB + uT 1MB) + P*2MB scores (FF ffb 32MB aliases region start)
  int P = 0;
  if      (rem >= 128 * MBc) P = 32;   // attn 128 MB
  else if (rem >= 64 * MBc)  P = 8;    // attn 32 MB (ffb 32MB fits too)
  if (P == 0) {
    fill_kernel<<<1024, 256, 0, stream>>>((float*)d_out, (long long)out_size,
                                          (float)(ws_size >> 20));
    return;
  }

  char* A = p;
  const long long pairE = (long long)S_LEN * HD;
  bf16_t* qc  = (bf16_t*)A;                        // y per pair
  bf16_t* uTc = qc  + (long long)P * pairE;        // uT per pair (u = x@U, U=Wv@Wo)
  bf16_t* scb = uTc + (long long)P * pairE;        // bf16 scores, softmax in-place
  bf16_t* ffb = (bf16_t*)A;                        // FF phase alias (32 MB; qc dead)
  // prep scratch (in A; dead once layer loop starts): [wq|wk] 24MB, wv 6MB, woT 6MB
  bf16_t* wqkb = (bf16_t*)A;                        // 24 MB
  bf16_t* wvb  = wqkb + 24LL * HD * HD;             // 6 MB
  bf16_t* woTa = wvb  + 12LL * HD * HD;             // 6 MB (3x [HD][FFD])

  const dim3 tb(32, 8);
  // -------- one-time weight prep (batched over all 3 layers) --------
  transpose_kernel<float><<<dim3(4,16,1), tb, 0, stream>>>(lm_w, lmT, HD, NTOK, 0, 0);
  convert2_kernel<<<4096, 256, 0, stream>>>(wq, wk, wqkb, 12LL*HD*HD);
  convert2_kernel<<<2048, 256, 0, stream>>>(wv, wv + 6LL*HD*HD, wvb, 6LL*HD*HD);
  transpose_kernel<float><<<dim3(16,64,3), tb, 0, stream>>>(
    wo_w, woTa, FFD, HD, (long long)FFD*HD, (long long)HD*FFD);
  convert2_kernel<<<4096, 256, 0, stream>>>(ff1_w, ff2_w, wffa, 3LL*FFD*HD);
  // Gt[l*4+h] = Wk[l,h] @ Wq[l,h]^T  (z=12; contiguous strides across l,h)
  gemm_bt_kernel<true,false,false,false,false><<<dim3(4,4,12),256,0,stream>>>(
    wqkb + 12LL*HD*HD, wqkb, nullptr, Gt3,
    HD, HD, HD, HD, HD, HD,
    (long long)HD*HD, (long long)HD*HD, 0, 0,
    30, 0, (long long)HD*HD,
    30, 0, 1.f);
  // UT[l*4+h] = (Wv[l,h] @ Wo[l])^T : A=woT[l] col block h, B=wv[l,h] (per-layer launch)
  for (int l = 0; l < NBLK; ++l)
    gemm_bt_kernel<true,false,false,false,false><<<dim3(4,4,4),256,0,stream>>>(
      woTa + (long long)l*HD*FFD, wvb + (long long)l*4*HD*HD, nullptr,
      UT3 + (long long)l*4*HD*HD,
      HD, HD, HD, FFD, HD, HD,
      512, (long long)HD*HD, 0, 0,
      30, 0, (long long)HD*HD,
      30, 0, 1.f);

  pos_kernel<<<BATCH, S_LEN, 0, stream>>>(amask, pos);
  embed_kernel<<<8192, 256, 0, stream>>>(ids, amask, pos, emb, x, xb);

  const int nch = 32 / P;
  const int bpc = P / NHEAD;

  for (int l = 0; l < NBLK; ++l) {
    const bf16_t* Gt  = Gt3 + (long long)l*4*HD*HD;
    const bf16_t* UT  = UT3 + (long long)l*4*HD*HD;
    const bf16_t* wf1 = wffa + (long long)l*FFD*HD;
    const bf16_t* wf2 = wffa + 3LL*FFD*HD + (long long)l*HD*FFD;

    for (int c = 0; c < nch; ++c) {
      const int b0 = c * bpc;
      const int pair0 = b0 * NHEAD;
      const int Mch = bpc * S_LEN;

      // y = x @ G per head (z = head): replaces q AND k projections
      gemm256_kernel<true,false,false,false,false,false><<<dim3(Mch/256,2,4),512,0,stream>>>(
        xb + (long long)b0*S_LEN*HD, Gt, nullptr, qc, Mch, HD, HD, HD, HD, HD,
        0, (long long)HD*HD, 0, 0,
        2, 0, pairE,
        10, (long long)NHEAD*pairE, 1.f);

      // uT[pair][f][t] = sum_c UT[h][f][c] * xb[b,t,c]   (u = x@U; PV B-operand)
      gemm256_kernel<true,false,false,false,false,false><<<dim3(8,4,bpc),512,0,stream>>>(
        UT, xb + (long long)b0*S_LEN*HD, nullptr, uTc,
        2048, S_LEN, HD, HD, HD, S_LEN,
        0, (long long)S_LEN*HD, 0, 0,
        0, (long long)NHEAD*HD*S_LEN, 0,
        9, (long long)HD*S_LEN, 1.f);

      // scores = y @ xb^T / sqrt(512) -> bf16 scb. 128^2 tiles (CSKIP causal),
      // fine-grain backfill (r16). B shared per 4 heads.
      gemm_bt_kernel<true,false,false,true,false><<<dim3(8,8,P),256,0,stream>>>(
        qc, xb + (long long)b0*S_LEN*HD, nullptr, scb,
        S_LEN, S_LEN, HD, HD, HD, S_LEN,
        pairE, (long long)S_LEN*HD, 2, 0,
        30, 0, (long long)S_LEN*S_LEN,
        30, 0, 0.044194173824159216f);
      softmax_kernel<<<dim3(S_LEN/4,P),256,0,stream>>>(scb, amask, pair0);
      // head-partial mh_h = P~_h @ u_h  -> ob[h][b*1024+s][*] bf16 (z = b*4+h)
      gemm256_kernel<true,false,false,false,true,false><<<dim3(4,2,P),512,0,stream>>>(
        scb, uTc, nullptr, ob,
        S_LEN, HD, S_LEN, S_LEN, S_LEN, HD,
        (long long)S_LEN*S_LEN, (long long)HD*S_LEN, 0, 0,
        2, (long long)S_LEN*HD, (long long)MROW*HD,
        30, 0, 1.f);
    }

    // x = LN(x + sum_h ob[h] + wo_b)  (wo GEMM folded into U)
    lnb_kernel<<<2048,256,0,stream>>>(x, ob, (long long)MROW*HD,
                                      wo_b + l*HD, ln1_g + l*HD, ln1_b + l*HD, xb);

    // ff1: relu(xb @ ff1^T + b1) -> ffb (bf16)
    gemm256_kernel<true,true,true,false,false,false><<<dim3(32,8,1),512,0,stream>>>(
      xb, wf1, ff1_b + l*FFD, ffb,
      (int)MROW, FFD, HD, HD, HD, FFD,
      0, 0, 0, 0, 30, 0, 0, 30, 0, 1.f);
    // ff2: split-K=4 bf16 partials -> ob slots 0-3 (same instantiation as y-proj;
    //  r21: halves ff2 WRITE + ln2 READ vs f32 tmp)
    gemm256_kernel<true,false,false,false,false,false><<<dim3(32,2,4),512,0,stream>>>(
      ffb, wf2, nullptr, ob,
      (int)MROW, HD, FFD/4, FFD, FFD, HD,
      FFD/4, FFD/4, 0, 0,
      0, (long long)MROW*HD, 0,
      30, 0, 1.f);
    lnb_kernel<<<2048,256,0,stream>>>(x, ob, (long long)MROW*HD,
                                      ff2_b + l*HD, ln2_g + l*HD, ln2_b + l*HD, xb);
  }

  // lm head -> d_out (f32), N=128 -> 128-tile kernel
  gemm_bt_kernel<false,false,false,false,false><<<dim3(64,1,1),256,0,stream>>>(
    xb, lmT, nullptr, (float*)d_out,
    (int)MROW, NTOK, HD, HD, HD, NTOK,
    0, 0, 0, 0, 30, 0, 0, 30, 0, 1.f);
}